// Round 3
// baseline (2294.801 us; speedup 1.0000x reference)
//
#include <hip/hip_runtime.h>

#define TT 96
#define FF 32
#define HH 128
#define G4 512
#define LOG2E 1.4426950408889634f

__device__ __forceinline__ float fexp2(float x){ return __builtin_amdgcn_exp2f(x); }
__device__ __forceinline__ float frcp(float x){ return __builtin_amdgcn_rcpf(x); }
__device__ __forceinline__ float fsigmoid(float x){ return frcp(1.0f + fexp2(-LOG2E*x)); }
__device__ __forceinline__ float ftanh(float x){
    float u = fexp2(2.0f*LOG2E*x);
    return 1.0f - 2.0f*frcp(1.0f + u);
}
__device__ __forceinline__ unsigned rne_bf16(float f){
    unsigned u = __float_as_uint(f);
    return (u + 0x7fffu + ((u >> 16) & 1u)) >> 16;
}
__device__ __forceinline__ unsigned pack2(float lo, float hi){
    return rne_bf16(lo) | (rne_bf16(hi) << 16);
}
__device__ __forceinline__ float bflo(unsigned q){ return __uint_as_float(q << 16); }
__device__ __forceinline__ float bfhi(unsigned q){ return __uint_as_float(q & 0xffff0000u); }

// ---------------------------------------------------------------------------
// k_prep: G = fc_w[0:128]@dec_k packed to bf16 pairs (uint4 of 8 k-values) in
// the exact LDS layout k_dec wants; gy = fc_w[128]@dec_k; gb = fc_b@dec_k+dec_b
// ---------------------------------------------------------------------------
__global__ __launch_bounds__(256) void k_prep(const float* __restrict__ fc_w,
                                              const float* __restrict__ fc_b,
                                              const float* __restrict__ dec_k,
                                              const float* __restrict__ dec_b,
                                              unsigned* __restrict__ Gp,
                                              float* __restrict__ gy,
                                              float* __restrict__ gb){
    int blk = blockIdx.x, tid = threadIdx.x;
    int u0 = tid, u1 = tid + 256;
    if (blk < 16){
        float a0[8], a1[8];
        #pragma unroll
        for (int r = 0; r < 8; ++r){ a0[r] = 0.f; a1[r] = 0.f; }
        for (int m = 0; m < 128; ++m){
            float d0 = dec_k[m*G4 + u0], d1 = dec_k[m*G4 + u1];
            #pragma unroll
            for (int r = 0; r < 8; ++r){
                float w = fc_w[(blk*8 + r)*HH + m];
                a0[r] += w * d0; a1[r] += w * d1;
            }
        }
        #pragma unroll
        for (int c = 0; c < 4; ++c){
            Gp[(blk*G4 + u0)*4 + c] = pack2(a0[2*c], a0[2*c+1]);
            Gp[(blk*G4 + u1)*4 + c] = pack2(a1[2*c], a1[2*c+1]);
        }
    } else if (blk == 16){
        float a0 = 0.f, a1 = 0.f;
        for (int m = 0; m < 128; ++m){
            float w = fc_w[128*HH + m];
            a0 += w * dec_k[m*G4 + u0]; a1 += w * dec_k[m*G4 + u1];
        }
        gy[u0] = a0; gy[u1] = a1;
    } else {
        float a0 = 0.f, a1 = 0.f;
        for (int m = 0; m < 128; ++m){
            float w = fc_b[m];
            a0 += w * dec_k[m*G4 + u0]; a1 += w * dec_k[m*G4 + u1];
        }
        gb[u0] = a0 + dec_b[u0]; gb[u1] = a1 + dec_b[u1];
    }
}

// ---------------------------------------------------------------------------
// k_enc: 512 threads, 1 gate-unit/thread. regs: wa[64] (att W1hs) + ra[128]
// (enc_r col). LDS: enc_k float4 [f4][u], XPJT (x-proj, [j][f] pad 33), XIN.
// __launch_bounds__(512,1): 1 block/CU -> 2 waves/SIMD -> 256 VGPR budget
// (second arg=2 was honored as 2 blocks/CU -> 128 VGPR cap -> scratch spill)
// ---------------------------------------------------------------------------
__global__ __launch_bounds__(512, 1) void k_enc(const float* __restrict__ inputs,
                                                const float* __restrict__ enc_k,
                                                const float* __restrict__ enc_r,
                                                const float* __restrict__ enc_b,
                                                const float* __restrict__ ae_w1,
                                                const float* __restrict__ ae_b1,
                                                const float* __restrict__ ae_w2,
                                                float* __restrict__ ws_xenc){
    extern __shared__ float lds[];
    float4* KL4  = (float4*)lds;          // [8][512] float4   (16384 words)
    float*  XPJT = lds + 16384;           // [128][33]         (4224)
    float*  XIN  = lds + 20608;           // [96][32]          (3072)
    float*  HST  = lds + 23680;           // 256: h, s
    float*  PP   = lds + 23936;           // 512 partials / z
    float*  PE   = lds + 24448;           // 128
    float*  XT   = lds + 24576;           // 32
    float*  W2E  = lds + 24608;           // 128
    float*  AB1E = lds + 24736;           // 128

    const int b = blockIdx.x, tid = threadIdx.x;
    const int u = tid, j7 = tid & 127, seg = tid >> 7;
    const float* xin_g = inputs + b*TT*FF;

    for (int i = tid; i < TT*FF; i += 512) XIN[i] = xin_g[i];
    for (int i = tid; i < 8*G4; i += 512){
        int f4 = i >> 9, uu = i & 511;
        float4 v;
        v.x = enc_k[(f4*4+0)*G4 + uu];
        v.y = enc_k[(f4*4+1)*G4 + uu];
        v.z = enc_k[(f4*4+2)*G4 + uu];
        v.w = enc_k[(f4*4+3)*G4 + uu];
        KL4[i] = v;
    }
    if (tid < 128){ W2E[tid] = ae_w2[tid]; AB1E[tid] = ae_b1[tid]; }
    if (tid < 256) HST[tid] = 0.f;

    float wa[64], ra[128];
    #pragma unroll
    for (int kk = 0; kk < 64; ++kk) wa[kk] = ae_w1[(seg*64 + kk)*HH + j7];
    #pragma unroll
    for (int k = 0; k < 128; ++k) ra[k] = enc_r[k*G4 + u];
    const float eb = enc_b[u];

    __syncthreads();

    // XPJT[j][f] = sum_t x[t][f] * ae_w1[(256+t)*128 + j]  (time-invariant)
    {
        int j = tid & 127, fh = tid >> 7;
        float acc[8];
        #pragma unroll
        for (int i = 0; i < 8; ++i) acc[i] = 0.f;
        for (int t = 0; t < TT; ++t){
            float w = ae_w1[(256 + t)*HH + j];
            #pragma unroll
            for (int i = 0; i < 8; ++i) acc[i] += XIN[t*FF + fh*8 + i] * w;
        }
        #pragma unroll
        for (int i = 0; i < 8; ++i) XPJT[j*33 + fh*8 + i] = acc[i];
    }
    __syncthreads();

    for (int t = 0; t < TT; ++t){
        // PH-A: attention projection partials over [h;s]
        {
            float a = 0.f;
            #pragma unroll
            for (int kk = 0; kk < 64; kk += 4){
                float4 h4 = *(const float4*)&HST[seg*64 + kk];
                a += h4.x*wa[kk] + h4.y*wa[kk+1] + h4.z*wa[kk+2] + h4.w*wa[kk+3];
            }
            PP[tid] = a;
        }
        __syncthreads();
        if (tid < 128) PE[tid] = PP[tid] + PP[128+tid] + PP[256+tid] + PP[384+tid] + AB1E[tid];
        __syncthreads();
        // PH-B: e[f] partials
        {
            int f = tid & 31, jg = tid >> 5;
            float acc = 0.f;
            #pragma unroll
            for (int i = 0; i < 8; ++i){
                int j = jg*8 + i;
                acc += ftanh(PE[j] + XPJT[j*33 + f]) * W2E[j];
            }
            PP[tid] = acc;
        }
        __syncthreads();
        // reduce + softmax + x_tilde on first 32 lanes
        if (tid < 32){
            float e = 0.f;
            #pragma unroll
            for (int g = 0; g < 16; ++g) e += PP[g*32 + tid];
            float m = e;
            #pragma unroll
            for (int d = 16; d; d >>= 1) m = fmaxf(m, __shfl_xor(m, d, 32));
            float p = fexp2((e - m)*LOG2E);
            float ss = p;
            #pragma unroll
            for (int d = 16; d; d >>= 1) ss += __shfl_xor(ss, d, 32);
            XT[tid] = p * frcp(ss) * XIN[t*FF + tid];
        }
        __syncthreads();
        // PH-D: z[u] = enc_b + x_tilde@enc_k + h@enc_r
        {
            float z = eb;
            #pragma unroll
            for (int f4 = 0; f4 < 8; ++f4){
                float4 xt4 = *(const float4*)&XT[f4*4];
                float4 kv = KL4[f4*G4 + u];
                z += xt4.x*kv.x + xt4.y*kv.y + xt4.z*kv.z + xt4.w*kv.w;
            }
            #pragma unroll
            for (int kk = 0; kk < 128; kk += 4){
                float4 h4 = *(const float4*)&HST[kk];
                z += h4.x*ra[kk] + h4.y*ra[kk+1] + h4.z*ra[kk+2] + h4.w*ra[kk+3];
            }
            PP[u] = z;
        }
        __syncthreads();
        // gates
        if (tid < 128){
            int j = tid;
            float iv = fsigmoid(PP[j]);
            float fv = fsigmoid(PP[128 + j]);
            float gv = ftanh(PP[256 + j]);
            float ov = fsigmoid(PP[384 + j]);
            float cn = fv * HST[128 + j] + iv * gv;
            float hn = ov * ftanh(cn);
            HST[128 + j] = cn;
            HST[j] = hn;
            ws_xenc[(b*TT + t)*HH + j] = hn;
        }
        __syncthreads();
    }
}

// ---------------------------------------------------------------------------
// k_xept: xeptT[b][j][t] = sum_k x_enc[b][t][k] * ad_w1[(256+k)*128 + j]
// ---------------------------------------------------------------------------
__global__ __launch_bounds__(256) void k_xept(const float* __restrict__ ws_xenc,
                                              const float* __restrict__ ad_w1,
                                              float* __restrict__ ws_xept){
    int b = blockIdx.x, q = blockIdx.y, tid = threadIdx.x;
    int j = tid & 127, th = tid >> 7;
    const float* xb = ws_xenc + b*TT*HH;
    float acc[12];
    #pragma unroll
    for (int i = 0; i < 12; ++i) acc[i] = 0.f;
    for (int k = 0; k < 128; ++k){
        float w = ad_w1[(256 + k)*HH + j];
        #pragma unroll
        for (int i = 0; i < 12; ++i){
            int tp = q*24 + th*12 + i;
            acc[i] += xb[tp*HH + k] * w;
        }
    }
    #pragma unroll
    for (int i = 0; i < 12; ++i){
        int tp = q*24 + th*12 + i;
        ws_xept[(b*HH + j)*TT + tp] = acc[i];
    }
}

// ---------------------------------------------------------------------------
// k_dec: 512 threads, 1 gate-unit/thread. regs: ra[128] (dec_r col, fp32) +
// wdc[64] (att W1dc quarter). LDS: G bf16 [k8][u] uint4, x_enc bf16 [t8][k].
// __launch_bounds__(512,1): see k_enc note — 256 VGPR budget, no spill.
// ---------------------------------------------------------------------------
__global__ __launch_bounds__(512, 1) void k_dec(const float* __restrict__ inputs,
                                                const float* __restrict__ dec_r,
                                                const float* __restrict__ ad_w1,
                                                const float* __restrict__ ad_b1,
                                                const float* __restrict__ ad_w2,
                                                const float* __restrict__ ff_w,
                                                const float* __restrict__ ff_b,
                                                const unsigned* __restrict__ Gp,
                                                const float* __restrict__ gy,
                                                const float* __restrict__ gb,
                                                const float* __restrict__ ws_xenc,
                                                const float* __restrict__ ws_xept,
                                                float* __restrict__ out){
    extern __shared__ float lds[];
    uint4*  G8  = (uint4*)lds;              // [16][512] uint4  (32768 words)
    uint4*  XE4 = (uint4*)(lds + 32768);    // [12][128] uint4  (6144 words)
    float*  DST = lds + 38912;              // 256: d, c
    float*  PP  = lds + 39168;              // 512 partials / z
    float*  APJ = lds + 39680;              // 128
    float*  BETA= lds + 39808;              // 128 (96 used, unnormalized)
    float*  CTX = lds + 39936;              // 128
    float*  W2L = lds + 40064;              // 128
    float*  SCAL= lds + 40192;              // 8: [0]=1/sum, [1]=y_t

    const int b = blockIdx.x, tid = threadIdx.x;
    const int u = tid, j7 = tid & 127, seg = tid >> 7;

    {
        unsigned* Gs = (unsigned*)G8;
        for (int i = tid; i < 16*G4*4; i += 512) Gs[i] = Gp[i];
    }
    {
        const float* xe_g = ws_xenc + b*TT*HH;
        for (int i = tid; i < 12*HH; i += 512){
            int t8 = i >> 7, k = i & 127;
            float x0 = xe_g[(t8*8+0)*HH + k], x1 = xe_g[(t8*8+1)*HH + k];
            float x2 = xe_g[(t8*8+2)*HH + k], x3 = xe_g[(t8*8+3)*HH + k];
            float x4 = xe_g[(t8*8+4)*HH + k], x5 = xe_g[(t8*8+5)*HH + k];
            float x6 = xe_g[(t8*8+6)*HH + k], x7 = xe_g[(t8*8+7)*HH + k];
            uint4 qq;
            qq.x = pack2(x0,x1); qq.y = pack2(x2,x3);
            qq.z = pack2(x4,x5); qq.w = pack2(x6,x7);
            XE4[i] = qq;
        }
    }
    if (tid < 128) W2L[tid] = ad_w2[tid];
    if (tid < 256) DST[tid] = 0.f;

    float ra[128], wdc[64];
    #pragma unroll
    for (int k = 0; k < 128; ++k) ra[k] = dec_r[k*G4 + u];
    #pragma unroll
    for (int kk = 0; kk < 64; ++kk) wdc[kk] = ad_w1[(seg*64 + kk)*HH + j7];
    const float gbr = gb[u], gyr = gy[u];
    const float ab1 = (tid < 128) ? ad_b1[tid] : 0.f;

    __syncthreads();

    const float* xeptb = ws_xept + b*HH*TT;

    for (int t = 0; t < TT; ++t){
        if (tid == 0) SCAL[1] = inputs[b*TT*FF + t*FF + (FF-1)];
        // PH-1: attention projection partials over [d;c]
        {
            float a = 0.f;
            #pragma unroll
            for (int kk = 0; kk < 64; kk += 4){
                float4 d4 = *(const float4*)&DST[seg*64 + kk];
                a += d4.x*wdc[kk] + d4.y*wdc[kk+1] + d4.z*wdc[kk+2] + d4.w*wdc[kk+3];
            }
            PP[tid] = a;
        }
        // PH-5a: z from d@dec_r (register column; only needs DST)
        float z = gbr;
        #pragma unroll
        for (int kk = 0; kk < 128; kk += 4){
            float4 d4 = *(const float4*)&DST[kk];
            z += d4.x*ra[kk] + d4.y*ra[kk+1] + d4.z*ra[kk+2] + d4.w*ra[kk+3];
        }
        __syncthreads();
        if (tid < 128) APJ[tid] = PP[tid] + PP[128+tid] + PP[256+tid] + PP[384+tid] + ab1;
        __syncthreads();
        // PH-2: e[t'] partials (4 j-chunks of 32)
        {
            int tp = tid & 127, jh = tid >> 7;
            float acc = 0.f;
            if (tp < TT){
                const float* xrow = xeptb + (jh*32)*TT + tp;
                #pragma unroll
                for (int jj = 0; jj < 32; ++jj){
                    int j = jh*32 + jj;
                    acc += ftanh(APJ[j] + xrow[jj*TT]) * W2L[j];
                }
            }
            PP[tid] = acc;
        }
        __syncthreads();
        // reduce + softmax over 96 on wave 0
        if (tid < 64){
            float ea = PP[tid] + PP[128+tid] + PP[256+tid] + PP[384+tid];
            float ebv = -3.0e38f;
            if (tid < 32) ebv = PP[64+tid] + PP[192+tid] + PP[320+tid] + PP[448+tid];
            float m = fmaxf(ea, ebv);
            #pragma unroll
            for (int d = 32; d; d >>= 1) m = fmaxf(m, __shfl_xor(m, d, 64));
            float pa = fexp2((ea - m)*LOG2E);
            float pb = (tid < 32) ? fexp2((ebv - m)*LOG2E) : 0.f;
            float ss = pa + pb;
            #pragma unroll
            for (int d = 32; d; d >>= 1) ss += __shfl_xor(ss, d, 64);
            BETA[tid] = pa;
            if (tid < 32) BETA[64 + tid] = pb;
            if (tid == 0) SCAL[0] = frcp(ss);
        }
        __syncthreads();
        // PH-4: ctx partials from bf16 x_enc
        {
            int k = tid & 127, th = tid >> 7;
            float a = 0.f;
            #pragma unroll
            for (int i = 0; i < 3; ++i){
                int t8 = th*3 + i;
                uint4 qq = XE4[t8*HH + k];
                float4 b0 = *(const float4*)&BETA[t8*8];
                float4 b1 = *(const float4*)&BETA[t8*8 + 4];
                a += b0.x*bflo(qq.x) + b0.y*bfhi(qq.x)
                   + b0.z*bflo(qq.y) + b0.w*bfhi(qq.y)
                   + b1.x*bflo(qq.z) + b1.y*bfhi(qq.z)
                   + b1.z*bflo(qq.w) + b1.w*bfhi(qq.w);
            }
            PP[tid] = a;
        }
        __syncthreads();
        if (tid < 128) CTX[tid] = (PP[tid] + PP[128+tid] + PP[256+tid] + PP[384+tid]) * SCAL[0];
        __syncthreads();
        // PH-5b: z += y*gy + ctx@G (bf16 G, b128 LDS reads)
        {
            float yt = SCAL[1];
            z += yt * gyr;
            #pragma unroll
            for (int k8 = 0; k8 < 16; ++k8){
                uint4 g = G8[k8*G4 + u];
                float4 c0 = *(const float4*)&CTX[k8*8];
                float4 c1 = *(const float4*)&CTX[k8*8 + 4];
                z += c0.x*bflo(g.x) + c0.y*bfhi(g.x)
                   + c0.z*bflo(g.y) + c0.w*bfhi(g.y)
                   + c1.x*bflo(g.z) + c1.y*bfhi(g.z)
                   + c1.z*bflo(g.w) + c1.w*bfhi(g.w);
            }
            PP[u] = z;
        }
        __syncthreads();
        // PH-6: gates
        if (tid < 128){
            int j = tid;
            float iv = fsigmoid(PP[j]);
            float fv = fsigmoid(PP[128 + j]);
            float gv = ftanh(PP[256 + j]);
            float ov = fsigmoid(PP[384 + j]);
            float cn = fv * DST[128 + j] + iv * gv;
            float hn = ov * ftanh(cn);
            DST[128 + j] = cn;
            DST[j] = hn;
        }
        __syncthreads();
    }

    // output: y_pred = [d_n, ctx] @ ff_w + ff_b
    {
        int jp = tid & 31, sg = tid >> 5;
        float a = 0.f;
        #pragma unroll
        for (int kk = 0; kk < 16; ++kk){
            int k = sg*16 + kk;
            float val = (k < 128) ? DST[k] : CTX[k - 128];
            a += val * ff_w[k*FF + jp];
        }
        PP[sg*32 + jp] = a;
    }
    __syncthreads();
    if (tid < 32){
        float o = ff_b[tid];
        #pragma unroll
        for (int s = 0; s < 16; ++s) o += PP[s*32 + tid];
        out[b*FF + tid] = o;
    }
}

// ---------------------------------------------------------------------------
extern "C" void kernel_launch(void* const* d_in, const int* in_sizes, int n_in,
                              void* d_out, int out_size, void* d_ws, size_t ws_size,
                              hipStream_t stream) {
    const float* inputs = (const float*)d_in[0];
    const float* enc_k  = (const float*)d_in[1];
    const float* enc_r  = (const float*)d_in[2];
    const float* enc_b  = (const float*)d_in[3];
    const float* ae_w1  = (const float*)d_in[4];
    const float* ae_b1  = (const float*)d_in[5];
    const float* ae_w2  = (const float*)d_in[6];
    // d_in[7] = ae_b2 (softmax-invariant, unused)
    const float* dec_k  = (const float*)d_in[8];
    const float* dec_r  = (const float*)d_in[9];
    const float* dec_b  = (const float*)d_in[10];
    const float* ad_w1  = (const float*)d_in[11];
    const float* ad_b1  = (const float*)d_in[12];
    const float* ad_w2  = (const float*)d_in[13];
    // d_in[14] = ad_b2 (softmax-invariant, unused)
    const float* fc_w   = (const float*)d_in[15];
    const float* fc_b   = (const float*)d_in[16];
    const float* ff_w   = (const float*)d_in[17];
    const float* ff_b   = (const float*)d_in[18];

    float* ws      = (float*)d_ws;
    float* ws_xenc = ws;                         // 64*96*128 floats
    float* ws_xept = ws + 786432;                // 64*128*96 floats
    unsigned* Gp   = (unsigned*)(ws + 1572864);  // 32768 uints
    float* gy      = ws + 1605632;               // 512
    float* gb      = ws + 1606144;               // 512

    hipFuncSetAttribute((const void*)k_enc, hipFuncAttributeMaxDynamicSharedMemorySize, 99456);
    hipFuncSetAttribute((const void*)k_dec, hipFuncAttributeMaxDynamicSharedMemorySize, 160800);

    k_prep<<<18, 256, 0, stream>>>(fc_w, fc_b, dec_k, dec_b, Gp, gy, gb);
    k_enc<<<64, 512, 99456, stream>>>(inputs, enc_k, enc_r, enc_b, ae_w1, ae_b1, ae_w2, ws_xenc);
    k_xept<<<dim3(64, 4), 256, 0, stream>>>(ws_xenc, ad_w1, ws_xept);
    k_dec<<<64, 512, 160800, stream>>>(inputs, dec_r, ad_w1, ad_b1, ad_w2, ff_w, ff_b,
                                       Gp, gy, gb, ws_xenc, ws_xept, (float*)d_out);
}

// Round 4
// 1238.010 us; speedup vs baseline: 1.8536x; 1.8536x over previous
//
#include <hip/hip_runtime.h>

#define TT 96
#define FF 32
#define HH 128
#define G4 512
#define LOG2E 1.4426950408889634f

typedef _Float16 h2 __attribute__((ext_vector_type(2)));

__device__ __forceinline__ float fexp2(float x){ return __builtin_amdgcn_exp2f(x); }
__device__ __forceinline__ float frcp(float x){ return __builtin_amdgcn_rcpf(x); }
__device__ __forceinline__ float fsigmoid(float x){ return frcp(1.0f + fexp2(-LOG2E*x)); }
__device__ __forceinline__ float ftanh(float x){
    float u = fexp2(2.0f*LOG2E*x);
    return 1.0f - 2.0f*frcp(1.0f + u);
}
__device__ __forceinline__ h2 pk(float a, float b){
    h2 r; r.x = (_Float16)a; r.y = (_Float16)b; return r;   // RNE cvt
}
__device__ __forceinline__ float fdot2(h2 a, h2 b, float c){
#if __has_builtin(__builtin_amdgcn_fdot2)
    return __builtin_amdgcn_fdot2(a, b, c, false);          // v_dot2_f32_f16
#else
    return c + (float)a.x*(float)b.x + (float)a.y*(float)b.y;
#endif
}

// ---------------------------------------------------------------------------
// k_prep: G = fc_w[0:128]@dec_k packed to f16 pairs in k_dec's LDS layout
// (group g of 8 k's: element [(g*512+u)*4+c] = (G[8g+2c][u], G[8g+2c+1][u]));
// gy = fc_w[128]@dec_k; gb = fc_b@dec_k + dec_b (both fp32).
// ---------------------------------------------------------------------------
__global__ __launch_bounds__(256) void k_prep(const float* __restrict__ fc_w,
                                              const float* __restrict__ fc_b,
                                              const float* __restrict__ dec_k,
                                              const float* __restrict__ dec_b,
                                              h2* __restrict__ Gp,
                                              float* __restrict__ gy,
                                              float* __restrict__ gb){
    int blk = blockIdx.x, tid = threadIdx.x;
    int u0 = tid, u1 = tid + 256;
    if (blk < 16){
        float a0[8], a1[8];
        #pragma unroll
        for (int r = 0; r < 8; ++r){ a0[r] = 0.f; a1[r] = 0.f; }
        for (int m = 0; m < 128; ++m){
            float d0 = dec_k[m*G4 + u0], d1 = dec_k[m*G4 + u1];
            #pragma unroll
            for (int r = 0; r < 8; ++r){
                float w = fc_w[(blk*8 + r)*HH + m];
                a0[r] += w * d0; a1[r] += w * d1;
            }
        }
        #pragma unroll
        for (int c = 0; c < 4; ++c){
            Gp[(blk*G4 + u0)*4 + c] = pk(a0[2*c], a0[2*c+1]);
            Gp[(blk*G4 + u1)*4 + c] = pk(a1[2*c], a1[2*c+1]);
        }
    } else if (blk == 16){
        float a0 = 0.f, a1 = 0.f;
        for (int m = 0; m < 128; ++m){
            float w = fc_w[128*HH + m];
            a0 += w * dec_k[m*G4 + u0]; a1 += w * dec_k[m*G4 + u1];
        }
        gy[u0] = a0; gy[u1] = a1;
    } else {
        float a0 = 0.f, a1 = 0.f;
        for (int m = 0; m < 128; ++m){
            float w = fc_b[m];
            a0 += w * dec_k[m*G4 + u0]; a1 += w * dec_k[m*G4 + u1];
        }
        gb[u0] = a0 + dec_b[u0]; gb[u1] = a1 + dec_b[u1];
    }
}

// ---------------------------------------------------------------------------
// k_enc: 512 threads, 1 gate-unit/thread. Designed for the observed 128-VGPR
// cap on 512-thread workgroups: weight columns as f16-pair register arrays
// (rp_e[64] + wa_p[32] = 96 regs), consumed via v_dot2_f32_f16.
// ---------------------------------------------------------------------------
__global__ __launch_bounds__(512, 1) void k_enc(const float* __restrict__ inputs,
                                                const float* __restrict__ enc_k,
                                                const float* __restrict__ enc_r,
                                                const float* __restrict__ enc_b,
                                                const float* __restrict__ ae_w1,
                                                const float* __restrict__ ae_b1,
                                                const float* __restrict__ ae_w2,
                                                float* __restrict__ ws_xenc){
    extern __shared__ float lds[];
    float4* KL4  = (float4*)lds;          // [8][512] float4   (16384 words)
    float*  XPJT = lds + 16384;           // [128][33]         (4224)
    float*  XIN  = lds + 20608;           // [96][32]          (3072)
    float*  HST  = lds + 23680;           // 256: h, s (fp32 state)
    float*  PP   = lds + 23936;           // 512 partials / z
    float*  PE   = lds + 24448;           // 128
    float*  XT   = lds + 24576;           // 32
    float*  W2E  = lds + 24608;           // 128
    float*  AB1E = lds + 24736;           // 128
    h2*     HSP  = (h2*)(lds + 24864);    // 128: packed [h;s] pairs

    const int b = blockIdx.x, tid = threadIdx.x;
    const int u = tid, j7 = tid & 127, seg = tid >> 7;
    const float* xin_g = inputs + b*TT*FF;

    for (int i = tid; i < TT*FF; i += 512) XIN[i] = xin_g[i];
    for (int i = tid; i < 8*G4; i += 512){
        int f4 = i >> 9, uu = i & 511;
        float4 v;
        v.x = enc_k[(f4*4+0)*G4 + uu];
        v.y = enc_k[(f4*4+1)*G4 + uu];
        v.z = enc_k[(f4*4+2)*G4 + uu];
        v.w = enc_k[(f4*4+3)*G4 + uu];
        KL4[i] = v;
    }
    if (tid < 128){ W2E[tid] = ae_w2[tid]; AB1E[tid] = ae_b1[tid]; HSP[tid] = pk(0.f, 0.f); }
    if (tid < 256) HST[tid] = 0.f;

    // packed f16 weight columns in registers
    h2 wa_p[32], rp_e[64];
    #pragma unroll
    for (int i = 0; i < 32; ++i)
        wa_p[i] = pk(ae_w1[(seg*64 + 2*i)*HH + j7], ae_w1[(seg*64 + 2*i+1)*HH + j7]);
    #pragma unroll
    for (int i = 0; i < 64; ++i)
        rp_e[i] = pk(enc_r[(2*i)*G4 + u], enc_r[(2*i+1)*G4 + u]);
    const float eb = enc_b[u];

    __syncthreads();

    // XPJT[j][f] = sum_t x[t][f] * ae_w1[(256+t)*128 + j]  (time-invariant)
    {
        int j = tid & 127, fh = tid >> 7;
        float acc[8];
        #pragma unroll
        for (int i = 0; i < 8; ++i) acc[i] = 0.f;
        for (int t = 0; t < TT; ++t){
            float w = ae_w1[(256 + t)*HH + j];
            #pragma unroll
            for (int i = 0; i < 8; ++i) acc[i] += XIN[t*FF + fh*8 + i] * w;
        }
        #pragma unroll
        for (int i = 0; i < 8; ++i) XPJT[j*33 + fh*8 + i] = acc[i];
    }
    __syncthreads();

    for (int t = 0; t < TT; ++t){
        // PH-A: attention projection partials over packed [h;s]
        {
            float a = 0.f;
            const h2* hp = &HSP[seg*32];
            #pragma unroll
            for (int i = 0; i < 32; ++i) a = fdot2(hp[i], wa_p[i], a);
            PP[tid] = a;
        }
        __syncthreads();
        if (tid < 128) PE[tid] = PP[tid] + PP[128+tid] + PP[256+tid] + PP[384+tid] + AB1E[tid];
        __syncthreads();
        // PH-B: e[f] partials
        {
            int f = tid & 31, jg = tid >> 5;
            float acc = 0.f;
            #pragma unroll
            for (int i = 0; i < 8; ++i){
                int j = jg*8 + i;
                acc += ftanh(PE[j] + XPJT[j*33 + f]) * W2E[j];
            }
            PP[tid] = acc;
        }
        __syncthreads();
        // reduce + softmax + x_tilde on first 32 lanes
        if (tid < 32){
            float e = 0.f;
            #pragma unroll
            for (int g = 0; g < 16; ++g) e += PP[g*32 + tid];
            float m = e;
            #pragma unroll
            for (int d = 16; d; d >>= 1) m = fmaxf(m, __shfl_xor(m, d, 32));
            float p = fexp2((e - m)*LOG2E);
            float ss = p;
            #pragma unroll
            for (int d = 16; d; d >>= 1) ss += __shfl_xor(ss, d, 32);
            XT[tid] = p * frcp(ss) * XIN[t*FF + tid];
        }
        __syncthreads();
        // PH-D: z[u] = enc_b + x_tilde@enc_k (fp32 LDS) + h@enc_r (f16 regs)
        {
            float z = eb;
            #pragma unroll
            for (int f4 = 0; f4 < 8; ++f4){
                float4 xt4 = *(const float4*)&XT[f4*4];
                float4 kv = KL4[f4*G4 + u];
                z += xt4.x*kv.x + xt4.y*kv.y + xt4.z*kv.z + xt4.w*kv.w;
            }
            #pragma unroll
            for (int i = 0; i < 64; ++i) z = fdot2(HSP[i], rp_e[i], z);
            PP[u] = z;
        }
        __syncthreads();
        // gates + packed-state update (pair exchange via shfl, no extra barrier)
        if (tid >= 128 && tid < 256){
            int j = tid - 128;
            float iv = fsigmoid(PP[j]);
            float fv = fsigmoid(PP[128 + j]);
            float gv = ftanh(PP[256 + j]);
            float ov = fsigmoid(PP[384 + j]);
            float cn = fv * HST[128 + j] + iv * gv;
            float hn = ov * ftanh(cn);
            HST[128 + j] = cn;
            HST[j] = hn;
            ws_xenc[(b*TT + t)*HH + j] = hn;
            float hn2 = __shfl_xor(hn, 1);
            float cn2 = __shfl_xor(cn, 1);
            if (!(j & 1)){
                HSP[j >> 1]        = pk(hn, hn2);   // h pairs
                HSP[64 + (j >> 1)] = pk(cn, cn2);   // s pairs
            }
        }
        __syncthreads();
    }
}

// ---------------------------------------------------------------------------
// k_xept: xeptT[b][j][t] = sum_k x_enc[b][t][k] * ad_w1[(256+k)*128 + j]
// ---------------------------------------------------------------------------
__global__ __launch_bounds__(256) void k_xept(const float* __restrict__ ws_xenc,
                                              const float* __restrict__ ad_w1,
                                              float* __restrict__ ws_xept){
    int b = blockIdx.x, q = blockIdx.y, tid = threadIdx.x;
    int j = tid & 127, th = tid >> 7;
    const float* xb = ws_xenc + b*TT*HH;
    float acc[12];
    #pragma unroll
    for (int i = 0; i < 12; ++i) acc[i] = 0.f;
    for (int k = 0; k < 128; ++k){
        float w = ad_w1[(256 + k)*HH + j];
        #pragma unroll
        for (int i = 0; i < 12; ++i){
            int tp = q*24 + th*12 + i;
            acc[i] += xb[tp*HH + k] * w;
        }
    }
    #pragma unroll
    for (int i = 0; i < 12; ++i){
        int tp = q*24 + th*12 + i;
        ws_xept[(b*HH + j)*TT + tp] = acc[i];
    }
}

// ---------------------------------------------------------------------------
// k_dec: 512 threads, 1 gate-unit/thread, 128-VGPR design:
// regs: rp[64] (dec_r col f16 pairs) + wp[32] (W1dc quarter f16 pairs).
// LDS: G f16 (128 KB, from k_prep), x_enc f16 pairs, packed activations.
// ---------------------------------------------------------------------------
__global__ __launch_bounds__(512, 1) void k_dec(const float* __restrict__ inputs,
                                                const float* __restrict__ dec_r,
                                                const float* __restrict__ ad_w1,
                                                const float* __restrict__ ad_b1,
                                                const float* __restrict__ ad_w2,
                                                const float* __restrict__ ff_w,
                                                const float* __restrict__ ff_b,
                                                const h2* __restrict__ Gp,
                                                const float* __restrict__ gy,
                                                const float* __restrict__ gb,
                                                const float* __restrict__ ws_xenc,
                                                const float* __restrict__ ws_xept,
                                                float* __restrict__ out){
    extern __shared__ float lds[];
    h2*    GH  = (h2*)lds;                // [16][512][4] h2 = 32768 words
    h2*    XEH = (h2*)(lds + 32768);      // [12][128][4] h2 = 6144 words
    float* DST = lds + 38912;             // 256: d, c (fp32 state)
    float* PP  = lds + 39168;             // 512 partials / z
    float* APJ = lds + 39680;             // 128
    float* CTX = lds + 39808;             // 128 (fp32, for final output)
    float* W2L = lds + 39936;             // 128
    float* SCAL= lds + 40064;             // 8: [0]=1/sum, [1]=y_t
    h2*    DCP = (h2*)(lds + 40072);      // 128: packed [d;c] pairs
    h2*    CXP = (h2*)(lds + 40200);      // 64: packed ctx pairs
    h2*    BEP = (h2*)(lds + 40264);      // 64 (48 used): packed beta pairs

    const int b = blockIdx.x, tid = threadIdx.x;
    const int u = tid, j7 = tid & 127, seg = tid >> 7;

    {   // G: global (f16-packed by k_prep) -> LDS, 16B chunks
        const uint4* gsrc = (const uint4*)Gp;
        uint4* gdst = (uint4*)GH;
        for (int i = tid; i < 8192; i += 512) gdst[i] = gsrc[i];
    }
    {   // x_enc -> LDS f16 t-pairs: XEH[(t8*128+k)*4+c] = (xe[8t8+2c][k], xe[8t8+2c+1][k])
        const float* xe_g = ws_xenc + b*TT*HH;
        for (int i = tid; i < 12*HH; i += 512){
            int t8 = i >> 7, k = i & 127;
            #pragma unroll
            for (int c = 0; c < 4; ++c)
                XEH[(t8*HH + k)*4 + c] = pk(xe_g[(t8*8 + 2*c)*HH + k], xe_g[(t8*8 + 2*c+1)*HH + k]);
        }
    }
    if (tid < 128){ W2L[tid] = ad_w2[tid]; DCP[tid] = pk(0.f, 0.f); }
    if (tid < 256) DST[tid] = 0.f;

    // packed f16 weight columns in registers
    h2 rp[64], wp[32];
    #pragma unroll
    for (int i = 0; i < 64; ++i)
        rp[i] = pk(dec_r[(2*i)*G4 + u], dec_r[(2*i+1)*G4 + u]);
    #pragma unroll
    for (int i = 0; i < 32; ++i)
        wp[i] = pk(ad_w1[(seg*64 + 2*i)*HH + j7], ad_w1[(seg*64 + 2*i+1)*HH + j7]);
    const float gbr = gb[u], gyr = gy[u];
    const float ab1 = (tid < 128) ? ad_b1[tid] : 0.f;

    __syncthreads();

    const float* xeptb = ws_xept + b*HH*TT;

    for (int t = 0; t < TT; ++t){
        if (tid == 0) SCAL[1] = inputs[b*TT*FF + t*FF + (FF-1)];
        // PH-1: attention projection partials over packed [d;c]
        {
            float a = 0.f;
            const h2* dp = &DCP[seg*32];
            #pragma unroll
            for (int i = 0; i < 32; ++i) a = fdot2(dp[i], wp[i], a);
            PP[tid] = a;
        }
        // PH-5a: z from d@dec_r (f16 reg column; reads only DCP d-pairs)
        float z = gbr;
        #pragma unroll
        for (int i = 0; i < 64; ++i) z = fdot2(DCP[i], rp[i], z);
        __syncthreads();
        if (tid < 128) APJ[tid] = PP[tid] + PP[128+tid] + PP[256+tid] + PP[384+tid] + ab1;
        __syncthreads();
        // PH-2: e[t'] partials (4 j-chunks of 32), fp32
        {
            int tp = tid & 127, jh = tid >> 7;
            float acc = 0.f;
            if (tp < TT){
                const float* xrow = xeptb + (jh*32)*TT + tp;
                #pragma unroll
                for (int jj = 0; jj < 32; ++jj){
                    int j = jh*32 + jj;
                    acc += ftanh(APJ[j] + xrow[jj*TT]) * W2L[j];
                }
            }
            PP[tid] = acc;
        }
        __syncthreads();
        // reduce + softmax over 96 on wave 0; write packed beta pairs
        if (tid < 64){
            float ea = PP[tid] + PP[128+tid] + PP[256+tid] + PP[384+tid];
            float ebv = -3.0e38f;
            if (tid < 32) ebv = PP[64+tid] + PP[192+tid] + PP[320+tid] + PP[448+tid];
            float m = fmaxf(ea, ebv);
            #pragma unroll
            for (int d = 32; d; d >>= 1) m = fmaxf(m, __shfl_xor(m, d, 64));
            float pa = fexp2((ea - m)*LOG2E);
            float pb = (tid < 32) ? fexp2((ebv - m)*LOG2E) : 0.f;
            float ss = pa + pb;
            #pragma unroll
            for (int d = 32; d; d >>= 1) ss += __shfl_xor(ss, d, 64);
            float pa2 = __shfl_xor(pa, 1);
            float pb2 = __shfl_xor(pb, 1);
            if (!(tid & 1)){
                BEP[tid >> 1] = pk(pa, pa2);
                if (tid < 32) BEP[32 + (tid >> 1)] = pk(pb, pb2);
            }
            if (tid == 0) SCAL[0] = frcp(ss);
        }
        __syncthreads();
        // PH-4: ctx partials from f16 x_enc (t-pairs) x packed beta
        {
            int k = tid & 127, th = tid >> 7;
            float a = 0.f;
            #pragma unroll
            for (int i = 0; i < 3; ++i){
                int t8 = th*3 + i;
                const h2* xp = &XEH[(t8*HH + k)*4];
                #pragma unroll
                for (int c = 0; c < 4; ++c) a = fdot2(xp[c], BEP[t8*4 + c], a);
            }
            PP[tid] = a;
        }
        __syncthreads();
        if (tid < 128){
            float cv = (PP[tid] + PP[128+tid] + PP[256+tid] + PP[384+tid]) * SCAL[0];
            CTX[tid] = cv;
            float cv2 = __shfl_xor(cv, 1);
            if (!(tid & 1)) CXP[tid >> 1] = pk(cv, cv2);
        }
        __syncthreads();
        // PH-5b: z += y*gy + ctx@G (f16 G in LDS, b128 reads)
        {
            z += SCAL[1] * gyr;
            #pragma unroll
            for (int g = 0; g < 16; ++g){
                const h2* gp = &GH[(g*G4 + u)*4];
                #pragma unroll
                for (int c = 0; c < 4; ++c) z = fdot2(gp[c], CXP[g*4 + c], z);
            }
            PP[u] = z;
        }
        __syncthreads();
        // PH-6: gates + packed-state update
        if (tid >= 128 && tid < 256){
            int j = tid - 128;
            float iv = fsigmoid(PP[j]);
            float fv = fsigmoid(PP[128 + j]);
            float gv = ftanh(PP[256 + j]);
            float ov = fsigmoid(PP[384 + j]);
            float cn = fv * DST[128 + j] + iv * gv;
            float hn = ov * ftanh(cn);
            DST[128 + j] = cn;
            DST[j] = hn;
            float hn2 = __shfl_xor(hn, 1);
            float cn2 = __shfl_xor(cn, 1);
            if (!(j & 1)){
                DCP[j >> 1]        = pk(hn, hn2);   // d pairs
                DCP[64 + (j >> 1)] = pk(cn, cn2);   // c pairs
            }
        }
        __syncthreads();
    }

    // output: y_pred = [d_n, ctx] @ ff_w + ff_b (fp32)
    {
        int jp = tid & 31, sg = tid >> 5;
        float a = 0.f;
        #pragma unroll
        for (int kk = 0; kk < 16; ++kk){
            int k = sg*16 + kk;
            float val = (k < 128) ? DST[k] : CTX[k - 128];
            a += val * ff_w[k*FF + jp];
        }
        PP[sg*32 + jp] = a;
    }
    __syncthreads();
    if (tid < 32){
        float o = ff_b[tid];
        #pragma unroll
        for (int s = 0; s < 16; ++s) o += PP[s*32 + tid];
        out[b*FF + tid] = o;
    }
}

// ---------------------------------------------------------------------------
extern "C" void kernel_launch(void* const* d_in, const int* in_sizes, int n_in,
                              void* d_out, int out_size, void* d_ws, size_t ws_size,
                              hipStream_t stream) {
    const float* inputs = (const float*)d_in[0];
    const float* enc_k  = (const float*)d_in[1];
    const float* enc_r  = (const float*)d_in[2];
    const float* enc_b  = (const float*)d_in[3];
    const float* ae_w1  = (const float*)d_in[4];
    const float* ae_b1  = (const float*)d_in[5];
    const float* ae_w2  = (const float*)d_in[6];
    // d_in[7] = ae_b2 (softmax-invariant, unused)
    const float* dec_k  = (const float*)d_in[8];
    const float* dec_r  = (const float*)d_in[9];
    const float* dec_b  = (const float*)d_in[10];
    const float* ad_w1  = (const float*)d_in[11];
    const float* ad_b1  = (const float*)d_in[12];
    const float* ad_w2  = (const float*)d_in[13];
    // d_in[14] = ad_b2 (softmax-invariant, unused)
    const float* fc_w   = (const float*)d_in[15];
    const float* fc_b   = (const float*)d_in[16];
    const float* ff_w   = (const float*)d_in[17];
    const float* ff_b   = (const float*)d_in[18];

    float* ws      = (float*)d_ws;
    float* ws_xenc = ws;                     // 64*96*128 floats
    float* ws_xept = ws + 786432;            // 64*128*96 floats
    h2*    Gp      = (h2*)(ws + 1572864);    // 32768 h2 (128 KB)
    float* gy      = ws + 1605632;           // 512
    float* gb      = ws + 1606144;           // 512

    hipFuncSetAttribute((const void*)k_enc, hipFuncAttributeMaxDynamicSharedMemorySize, 99968);
    hipFuncSetAttribute((const void*)k_dec, hipFuncAttributeMaxDynamicSharedMemorySize, 161312);

    k_prep<<<18, 256, 0, stream>>>(fc_w, fc_b, dec_k, dec_b, Gp, gy, gb);
    k_enc<<<64, 512, 99968, stream>>>(inputs, enc_k, enc_r, enc_b, ae_w1, ae_b1, ae_w2, ws_xenc);
    k_xept<<<dim3(64, 4), 256, 0, stream>>>(ws_xenc, ad_w1, ws_xept);
    k_dec<<<64, 512, 161312, stream>>>(inputs, dec_r, ad_w1, ad_b1, ad_w2, ff_w, ff_b,
                                       Gp, gy, gb, ws_xenc, ws_xept, (float*)d_out);
}

// Round 5
// 1069.417 us; speedup vs baseline: 2.1458x; 1.1577x over previous
//
#include <hip/hip_runtime.h>

#define TT 96
#define FF 32
#define HH 128
#define G4 512
#define LOG2E 1.4426950408889634f

typedef _Float16 h2 __attribute__((ext_vector_type(2)));

__device__ __forceinline__ float fexp2(float x){ return __builtin_amdgcn_exp2f(x); }
__device__ __forceinline__ float frcp(float x){ return __builtin_amdgcn_rcpf(x); }
__device__ __forceinline__ float fsigmoid(float x){ return frcp(1.0f + fexp2(-LOG2E*x)); }
__device__ __forceinline__ float ftanh(float x){
    float u = fexp2(2.0f*LOG2E*x);
    return 1.0f - 2.0f*frcp(1.0f + u);
}
__device__ __forceinline__ h2 pk(float a, float b){
    h2 r; r.x = (_Float16)a; r.y = (_Float16)b; return r;   // RNE cvt
}
__device__ __forceinline__ unsigned pku(float a, float b){
    return __builtin_bit_cast(unsigned, pk(a, b));
}
__device__ __forceinline__ h2 u2h(unsigned v){ return __builtin_bit_cast(h2, v); }
__device__ __forceinline__ float fdot2(h2 a, h2 b, float c){
#if __has_builtin(__builtin_amdgcn_fdot2)
    return __builtin_amdgcn_fdot2(a, b, c, false);          // v_dot2_f32_f16
#else
    return c + (float)a.x*(float)b.x + (float)a.y*(float)b.y;
#endif
}

// ---------------------------------------------------------------------------
// k_prep: G = fc_w[0:128]@dec_k packed to f16 pairs in k_dec's LDS layout
// (group g of 8 k's: element [(g*512+u)*4+c] = (G[8g+2c][u], G[8g+2c+1][u]));
// gy = fc_w[128]@dec_k; gb = fc_b@dec_k + dec_b (both fp32).
// ---------------------------------------------------------------------------
__global__ __launch_bounds__(256) void k_prep(const float* __restrict__ fc_w,
                                              const float* __restrict__ fc_b,
                                              const float* __restrict__ dec_k,
                                              const float* __restrict__ dec_b,
                                              h2* __restrict__ Gp,
                                              float* __restrict__ gy,
                                              float* __restrict__ gb){
    int blk = blockIdx.x, tid = threadIdx.x;
    int u0 = tid, u1 = tid + 256;
    if (blk < 16){
        float a0[8], a1[8];
        #pragma unroll
        for (int r = 0; r < 8; ++r){ a0[r] = 0.f; a1[r] = 0.f; }
        for (int m = 0; m < 128; ++m){
            float d0 = dec_k[m*G4 + u0], d1 = dec_k[m*G4 + u1];
            #pragma unroll
            for (int r = 0; r < 8; ++r){
                float w = fc_w[(blk*8 + r)*HH + m];
                a0[r] += w * d0; a1[r] += w * d1;
            }
        }
        #pragma unroll
        for (int c = 0; c < 4; ++c){
            Gp[(blk*G4 + u0)*4 + c] = pk(a0[2*c], a0[2*c+1]);
            Gp[(blk*G4 + u1)*4 + c] = pk(a1[2*c], a1[2*c+1]);
        }
    } else if (blk == 16){
        float a0 = 0.f, a1 = 0.f;
        for (int m = 0; m < 128; ++m){
            float w = fc_w[128*HH + m];
            a0 += w * dec_k[m*G4 + u0]; a1 += w * dec_k[m*G4 + u1];
        }
        gy[u0] = a0; gy[u1] = a1;
    } else {
        float a0 = 0.f, a1 = 0.f;
        for (int m = 0; m < 128; ++m){
            float w = fc_b[m];
            a0 += w * dec_k[m*G4 + u0]; a1 += w * dec_k[m*G4 + u1];
        }
        gb[u0] = a0 + dec_b[u0]; gb[u1] = a1 + dec_b[u1];
    }
}

// ---------------------------------------------------------------------------
// k_enc: 512 threads, 1 gate-unit/thread. 128-VGPR design: weight columns as
// f16-pair register arrays (rp_e[64] + wa_p[32] = 96 regs) via v_dot2_f32_f16.
// ---------------------------------------------------------------------------
__global__ __launch_bounds__(512, 1) void k_enc(const float* __restrict__ inputs,
                                                const float* __restrict__ enc_k,
                                                const float* __restrict__ enc_r,
                                                const float* __restrict__ enc_b,
                                                const float* __restrict__ ae_w1,
                                                const float* __restrict__ ae_b1,
                                                const float* __restrict__ ae_w2,
                                                float* __restrict__ ws_xenc){
    extern __shared__ float lds[];
    float4* KL4  = (float4*)lds;          // [8][512] float4   (16384 words)
    float*  XPJT = lds + 16384;           // [128][33]         (4224)
    float*  XIN  = lds + 20608;           // [96][32]          (3072)
    float*  HST  = lds + 23680;           // 256: h, s (fp32 state)
    float*  PP   = lds + 23936;           // 512 partials / z
    float*  PE   = lds + 24448;           // 128
    float*  XT   = lds + 24576;           // 32
    float*  W2E  = lds + 24608;           // 128
    float*  AB1E = lds + 24736;           // 128
    h2*     HSP  = (h2*)(lds + 24864);    // 128: packed [h;s] pairs

    const int b = blockIdx.x, tid = threadIdx.x;
    const int u = tid, j7 = tid & 127, seg = tid >> 7;
    const float* xin_g = inputs + b*TT*FF;

    for (int i = tid; i < TT*FF; i += 512) XIN[i] = xin_g[i];
    for (int i = tid; i < 8*G4; i += 512){
        int f4 = i >> 9, uu = i & 511;
        float4 v;
        v.x = enc_k[(f4*4+0)*G4 + uu];
        v.y = enc_k[(f4*4+1)*G4 + uu];
        v.z = enc_k[(f4*4+2)*G4 + uu];
        v.w = enc_k[(f4*4+3)*G4 + uu];
        KL4[i] = v;
    }
    if (tid < 128){ W2E[tid] = ae_w2[tid]; AB1E[tid] = ae_b1[tid]; HSP[tid] = pk(0.f, 0.f); }
    if (tid < 256) HST[tid] = 0.f;

    // packed f16 weight columns in registers
    h2 wa_p[32], rp_e[64];
    #pragma unroll
    for (int i = 0; i < 32; ++i)
        wa_p[i] = pk(ae_w1[(seg*64 + 2*i)*HH + j7], ae_w1[(seg*64 + 2*i+1)*HH + j7]);
    #pragma unroll
    for (int i = 0; i < 64; ++i)
        rp_e[i] = pk(enc_r[(2*i)*G4 + u], enc_r[(2*i+1)*G4 + u]);
    const float eb = enc_b[u];

    __syncthreads();

    // XPJT[j][f] = sum_t x[t][f] * ae_w1[(256+t)*128 + j]  (time-invariant)
    {
        int j = tid & 127, fh = tid >> 7;
        float acc[8];
        #pragma unroll
        for (int i = 0; i < 8; ++i) acc[i] = 0.f;
        for (int t = 0; t < TT; ++t){
            float w = ae_w1[(256 + t)*HH + j];
            #pragma unroll
            for (int i = 0; i < 8; ++i) acc[i] += XIN[t*FF + fh*8 + i] * w;
        }
        #pragma unroll
        for (int i = 0; i < 8; ++i) XPJT[j*33 + fh*8 + i] = acc[i];
    }
    __syncthreads();

    for (int t = 0; t < TT; ++t){
        // PH-A: attention projection partials over packed [h;s]
        {
            float a = 0.f;
            const h2* hp = &HSP[seg*32];
            #pragma unroll
            for (int i = 0; i < 32; ++i) a = fdot2(hp[i], wa_p[i], a);
            PP[tid] = a;
        }
        __syncthreads();
        if (tid < 128) PE[tid] = PP[tid] + PP[128+tid] + PP[256+tid] + PP[384+tid] + AB1E[tid];
        __syncthreads();
        // PH-B: e[f] partials
        {
            int f = tid & 31, jg = tid >> 5;
            float acc = 0.f;
            #pragma unroll
            for (int i = 0; i < 8; ++i){
                int j = jg*8 + i;
                acc += ftanh(PE[j] + XPJT[j*33 + f]) * W2E[j];
            }
            PP[tid] = acc;
        }
        __syncthreads();
        // reduce + softmax + x_tilde on first 32 lanes
        if (tid < 32){
            float e = 0.f;
            #pragma unroll
            for (int g = 0; g < 16; ++g) e += PP[g*32 + tid];
            float m = e;
            #pragma unroll
            for (int d = 16; d; d >>= 1) m = fmaxf(m, __shfl_xor(m, d, 32));
            float p = fexp2((e - m)*LOG2E);
            float ss = p;
            #pragma unroll
            for (int d = 16; d; d >>= 1) ss += __shfl_xor(ss, d, 32);
            XT[tid] = p * frcp(ss) * XIN[t*FF + tid];
        }
        __syncthreads();
        // PH-D: z[u] = enc_b + x_tilde@enc_k (fp32 LDS) + h@enc_r (f16 regs)
        {
            float z = eb;
            #pragma unroll
            for (int f4 = 0; f4 < 8; ++f4){
                float4 xt4 = *(const float4*)&XT[f4*4];
                float4 kv = KL4[f4*G4 + u];
                z += xt4.x*kv.x + xt4.y*kv.y + xt4.z*kv.z + xt4.w*kv.w;
            }
            #pragma unroll
            for (int i = 0; i < 64; ++i) z = fdot2(HSP[i], rp_e[i], z);
            PP[u] = z;
        }
        __syncthreads();
        // gates + packed-state update (pair exchange via shfl, no extra barrier)
        if (tid >= 128 && tid < 256){
            int j = tid - 128;
            float iv = fsigmoid(PP[j]);
            float fv = fsigmoid(PP[128 + j]);
            float gv = ftanh(PP[256 + j]);
            float ov = fsigmoid(PP[384 + j]);
            float cn = fv * HST[128 + j] + iv * gv;
            float hn = ov * ftanh(cn);
            HST[128 + j] = cn;
            HST[j] = hn;
            ws_xenc[(b*TT + t)*HH + j] = hn;
            float hn2 = __shfl_xor(hn, 1);
            float cn2 = __shfl_xor(cn, 1);
            if (!(j & 1)){
                HSP[j >> 1]        = pk(hn, hn2);   // h pairs
                HSP[64 + (j >> 1)] = pk(cn, cn2);   // s pairs
            }
        }
        __syncthreads();
    }
}

// ---------------------------------------------------------------------------
// k_xept: xeptT[b][j][t] = sum_k x_enc[b][t][k] * ad_w1[(256+k)*128 + j]
// ---------------------------------------------------------------------------
__global__ __launch_bounds__(256) void k_xept(const float* __restrict__ ws_xenc,
                                              const float* __restrict__ ad_w1,
                                              float* __restrict__ ws_xept){
    int b = blockIdx.x, q = blockIdx.y, tid = threadIdx.x;
    int j = tid & 127, th = tid >> 7;
    const float* xb = ws_xenc + b*TT*HH;
    float acc[12];
    #pragma unroll
    for (int i = 0; i < 12; ++i) acc[i] = 0.f;
    for (int k = 0; k < 128; ++k){
        float w = ad_w1[(256 + k)*HH + j];
        #pragma unroll
        for (int i = 0; i < 12; ++i){
            int tp = q*24 + th*12 + i;
            acc[i] += xb[tp*HH + k] * w;
        }
    }
    #pragma unroll
    for (int i = 0; i < 12; ++i){
        int tp = q*24 + th*12 + i;
        ws_xept[(b*HH + j)*TT + tp] = acc[i];
    }
}

// ---------------------------------------------------------------------------
// k_dec: 512 threads, 1 gate-unit/thread, 128-VGPR design.
// Round-5 fix: all 16B LDS h2-groups (GH, XEH) read/written as uint4 b128 —
// 4-byte reads at lane-stride-16B were 8-way bank conflicts (2.2e7 counted).
// ---------------------------------------------------------------------------
__global__ __launch_bounds__(512, 1) void k_dec(const float* __restrict__ inputs,
                                                const float* __restrict__ dec_r,
                                                const float* __restrict__ ad_w1,
                                                const float* __restrict__ ad_b1,
                                                const float* __restrict__ ad_w2,
                                                const float* __restrict__ ff_w,
                                                const float* __restrict__ ff_b,
                                                const h2* __restrict__ Gp,
                                                const float* __restrict__ gy,
                                                const float* __restrict__ gb,
                                                const float* __restrict__ ws_xenc,
                                                const float* __restrict__ ws_xept,
                                                float* __restrict__ out){
    extern __shared__ float lds[];
    uint4* GH4 = (uint4*)lds;             // [16][512] uint4 = 32768 words
    uint4* XE4 = (uint4*)(lds + 32768);   // [12][128] uint4 = 6144 words
    float* DST = lds + 38912;             // 256: d, c (fp32 state)
    float* PP  = lds + 39168;             // 512 partials / z
    float* APJ = lds + 39680;             // 128
    float* CTX = lds + 39808;             // 128 (fp32, for final output)
    float* W2L = lds + 39936;             // 128
    float* SCAL= lds + 40064;             // 8: [0]=1/sum
    h2*    DCP = (h2*)(lds + 40072);      // 128: packed [d;c] pairs
    h2*    CXP = (h2*)(lds + 40200);      // 64: packed ctx pairs
    h2*    BEP = (h2*)(lds + 40264);      // 64 (48 used): packed beta pairs
    float* YV  = lds + 40328;             // 96: y_prev values

    const int b = blockIdx.x, tid = threadIdx.x;
    const int u = tid, j7 = tid & 127, seg = tid >> 7;

    {   // G: global (f16-packed by k_prep) -> LDS, b128 both sides
        const uint4* gsrc = (const uint4*)Gp;
        for (int i = tid; i < 8192; i += 512) GH4[i] = gsrc[i];
    }
    {   // x_enc -> LDS f16 t-pairs, b128 writes:
        // XE4[t8*128+k] = {pk(xe[8t8][k],xe[8t8+1][k]), ..., pk(xe[8t8+6][k],xe[8t8+7][k])}
        const float* xe_g = ws_xenc + b*TT*HH;
        for (int i = tid; i < 12*HH; i += 512){
            int t8 = i >> 7, k = i & 127;
            uint4 qq;
            qq.x = pku(xe_g[(t8*8 + 0)*HH + k], xe_g[(t8*8 + 1)*HH + k]);
            qq.y = pku(xe_g[(t8*8 + 2)*HH + k], xe_g[(t8*8 + 3)*HH + k]);
            qq.z = pku(xe_g[(t8*8 + 4)*HH + k], xe_g[(t8*8 + 5)*HH + k]);
            qq.w = pku(xe_g[(t8*8 + 6)*HH + k], xe_g[(t8*8 + 7)*HH + k]);
            XE4[i] = qq;
        }
    }
    for (int i = tid; i < TT; i += 512) YV[i] = inputs[b*TT*FF + i*FF + (FF-1)];
    if (tid < 128){ W2L[tid] = ad_w2[tid]; DCP[tid] = pk(0.f, 0.f); }
    if (tid < 256) DST[tid] = 0.f;

    // packed f16 weight columns in registers
    h2 rp[64], wp[32];
    #pragma unroll
    for (int i = 0; i < 64; ++i)
        rp[i] = pk(dec_r[(2*i)*G4 + u], dec_r[(2*i+1)*G4 + u]);
    #pragma unroll
    for (int i = 0; i < 32; ++i)
        wp[i] = pk(ad_w1[(seg*64 + 2*i)*HH + j7], ad_w1[(seg*64 + 2*i+1)*HH + j7]);
    const float gbr = gb[u], gyr = gy[u];
    const float ab1 = (tid < 128) ? ad_b1[tid] : 0.f;

    __syncthreads();

    const float* xeptb = ws_xept + b*HH*TT;

    for (int t = 0; t < TT; ++t){
        // PH-1: attention projection partials over packed [d;c]
        {
            float a = 0.f;
            const h2* dp = &DCP[seg*32];
            #pragma unroll
            for (int i = 0; i < 32; ++i) a = fdot2(dp[i], wp[i], a);
            PP[tid] = a;
        }
        // PH-5a: z from d@dec_r (f16 reg column; reads only DCP d-pairs)
        float z = gbr;
        #pragma unroll
        for (int i = 0; i < 64; ++i) z = fdot2(DCP[i], rp[i], z);
        __syncthreads();
        if (tid < 128) APJ[tid] = PP[tid] + PP[128+tid] + PP[256+tid] + PP[384+tid] + ab1;
        __syncthreads();
        // PH-2: e[t'] partials (4 j-chunks of 32), fp32
        {
            int tp = tid & 127, jh = tid >> 7;
            float acc = 0.f;
            if (tp < TT){
                const float* xrow = xeptb + (jh*32)*TT + tp;
                #pragma unroll
                for (int jj = 0; jj < 32; ++jj){
                    int j = jh*32 + jj;
                    acc += ftanh(APJ[j] + xrow[jj*TT]) * W2L[j];
                }
            }
            PP[tid] = acc;
        }
        __syncthreads();
        // reduce + softmax over 96 on wave 0; write packed beta pairs
        if (tid < 64){
            float ea = PP[tid] + PP[128+tid] + PP[256+tid] + PP[384+tid];
            float ebv = -3.0e38f;
            if (tid < 32) ebv = PP[64+tid] + PP[192+tid] + PP[320+tid] + PP[448+tid];
            float m = fmaxf(ea, ebv);
            #pragma unroll
            for (int d = 32; d; d >>= 1) m = fmaxf(m, __shfl_xor(m, d, 64));
            float pa = fexp2((ea - m)*LOG2E);
            float pb = (tid < 32) ? fexp2((ebv - m)*LOG2E) : 0.f;
            float ss = pa + pb;
            #pragma unroll
            for (int d = 32; d; d >>= 1) ss += __shfl_xor(ss, d, 64);
            float pa2 = __shfl_xor(pa, 1);
            float pb2 = __shfl_xor(pb, 1);
            if (!(tid & 1)){
                BEP[tid >> 1] = pk(pa, pa2);
                if (tid < 32) BEP[32 + (tid >> 1)] = pk(pb, pb2);
            }
            if (tid == 0) SCAL[0] = frcp(ss);
        }
        __syncthreads();
        // PH-4: ctx partials — b128 read of 8 packed x_enc t-values
        {
            int k = tid & 127, th = tid >> 7;
            float a = 0.f;
            #pragma unroll
            for (int i = 0; i < 3; ++i){
                int t8 = th*3 + i;
                uint4 q = XE4[t8*HH + k];
                a = fdot2(u2h(q.x), BEP[t8*4 + 0], a);
                a = fdot2(u2h(q.y), BEP[t8*4 + 1], a);
                a = fdot2(u2h(q.z), BEP[t8*4 + 2], a);
                a = fdot2(u2h(q.w), BEP[t8*4 + 3], a);
            }
            PP[tid] = a;
        }
        __syncthreads();
        if (tid < 128){
            float cv = (PP[tid] + PP[128+tid] + PP[256+tid] + PP[384+tid]) * SCAL[0];
            CTX[tid] = cv;
            float cv2 = __shfl_xor(cv, 1);
            if (!(tid & 1)) CXP[tid >> 1] = pk(cv, cv2);
        }
        __syncthreads();
        // PH-5b: z += y*gy + ctx@G — b128 read of 8 packed G k-values
        {
            z += YV[t] * gyr;
            #pragma unroll
            for (int g = 0; g < 16; ++g){
                uint4 q = GH4[g*G4 + u];
                z = fdot2(u2h(q.x), CXP[g*4 + 0], z);
                z = fdot2(u2h(q.y), CXP[g*4 + 1], z);
                z = fdot2(u2h(q.z), CXP[g*4 + 2], z);
                z = fdot2(u2h(q.w), CXP[g*4 + 3], z);
            }
            PP[u] = z;
        }
        __syncthreads();
        // PH-6: gates + packed-state update
        if (tid >= 128 && tid < 256){
            int j = tid - 128;
            float iv = fsigmoid(PP[j]);
            float fv = fsigmoid(PP[128 + j]);
            float gv = ftanh(PP[256 + j]);
            float ov = fsigmoid(PP[384 + j]);
            float cn = fv * DST[128 + j] + iv * gv;
            float hn = ov * ftanh(cn);
            DST[128 + j] = cn;
            DST[j] = hn;
            float hn2 = __shfl_xor(hn, 1);
            float cn2 = __shfl_xor(cn, 1);
            if (!(j & 1)){
                DCP[j >> 1]        = pk(hn, hn2);   // d pairs
                DCP[64 + (j >> 1)] = pk(cn, cn2);   // c pairs
            }
        }
        __syncthreads();
    }

    // output: y_pred = [d_n, ctx] @ ff_w + ff_b (fp32)
    {
        int jp = tid & 31, sg = tid >> 5;
        float a = 0.f;
        #pragma unroll
        for (int kk = 0; kk < 16; ++kk){
            int k = sg*16 + kk;
            float val = (k < 128) ? DST[k] : CTX[k - 128];
            a += val * ff_w[k*FF + jp];
        }
        PP[sg*32 + jp] = a;
    }
    __syncthreads();
    if (tid < 32){
        float o = ff_b[tid];
        #pragma unroll
        for (int s = 0; s < 16; ++s) o += PP[s*32 + tid];
        out[b*FF + tid] = o;
    }
}

// ---------------------------------------------------------------------------
extern "C" void kernel_launch(void* const* d_in, const int* in_sizes, int n_in,
                              void* d_out, int out_size, void* d_ws, size_t ws_size,
                              hipStream_t stream) {
    const float* inputs = (const float*)d_in[0];
    const float* enc_k  = (const float*)d_in[1];
    const float* enc_r  = (const float*)d_in[2];
    const float* enc_b  = (const float*)d_in[3];
    const float* ae_w1  = (const float*)d_in[4];
    const float* ae_b1  = (const float*)d_in[5];
    const float* ae_w2  = (const float*)d_in[6];
    // d_in[7] = ae_b2 (softmax-invariant, unused)
    const float* dec_k  = (const float*)d_in[8];
    const float* dec_r  = (const float*)d_in[9];
    const float* dec_b  = (const float*)d_in[10];
    const float* ad_w1  = (const float*)d_in[11];
    const float* ad_b1  = (const float*)d_in[12];
    const float* ad_w2  = (const float*)d_in[13];
    // d_in[14] = ad_b2 (softmax-invariant, unused)
    const float* fc_w   = (const float*)d_in[15];
    const float* fc_b   = (const float*)d_in[16];
    const float* ff_w   = (const float*)d_in[17];
    const float* ff_b   = (const float*)d_in[18];

    float* ws      = (float*)d_ws;
    float* ws_xenc = ws;                     // 64*96*128 floats
    float* ws_xept = ws + 786432;            // 64*128*96 floats
    h2*    Gp      = (h2*)(ws + 1572864);    // 32768 h2 (128 KB)
    float* gy      = ws + 1605632;           // 512
    float* gb      = ws + 1606144;           // 512

    hipFuncSetAttribute((const void*)k_enc, hipFuncAttributeMaxDynamicSharedMemorySize, 99968);
    hipFuncSetAttribute((const void*)k_dec, hipFuncAttributeMaxDynamicSharedMemorySize, 161728);

    k_prep<<<18, 256, 0, stream>>>(fc_w, fc_b, dec_k, dec_b, Gp, gy, gb);
    k_enc<<<64, 512, 99968, stream>>>(inputs, enc_k, enc_r, enc_b, ae_w1, ae_b1, ae_w2, ws_xenc);
    k_xept<<<dim3(64, 4), 256, 0, stream>>>(ws_xenc, ad_w1, ws_xept);
    k_dec<<<64, 512, 161728, stream>>>(inputs, dec_r, ad_w1, ad_b1, ad_w2, ff_w, ff_b,
                                       Gp, gy, gb, ws_xenc, ws_xept, (float*)d_out);
}

// Round 6
// 1034.181 us; speedup vs baseline: 2.2190x; 1.0341x over previous
//
#include <hip/hip_runtime.h>

#define TT 96
#define FF 32
#define HH 128
#define G4 512
#define LOG2E 1.4426950408889634f

typedef _Float16 h2 __attribute__((ext_vector_type(2)));

__device__ __forceinline__ float fexp2(float x){ return __builtin_amdgcn_exp2f(x); }
__device__ __forceinline__ float frcp(float x){ return __builtin_amdgcn_rcpf(x); }
__device__ __forceinline__ float fsigmoid(float x){ return frcp(1.0f + fexp2(-LOG2E*x)); }
__device__ __forceinline__ float ftanh(float x){
    float u = fexp2(2.0f*LOG2E*x);
    return 1.0f - 2.0f*frcp(1.0f + u);
}
__device__ __forceinline__ h2 pk(float a, float b){
    h2 r; r.x = (_Float16)a; r.y = (_Float16)b; return r;   // RNE cvt
}
__device__ __forceinline__ unsigned pku(float a, float b){
    return __builtin_bit_cast(unsigned, pk(a, b));
}
__device__ __forceinline__ h2 u2h(unsigned v){ return __builtin_bit_cast(h2, v); }
__device__ __forceinline__ float fdot2(h2 a, h2 b, float c){
#if __has_builtin(__builtin_amdgcn_fdot2)
    return __builtin_amdgcn_fdot2(a, b, c, false);          // v_dot2_f32_f16
#else
    return c + (float)a.x*(float)b.x + (float)a.y*(float)b.y;
#endif
}

// ---------------------------------------------------------------------------
// k_prep: G = fc_w[0:128]@dec_k packed to f16 pairs, layout [g][u] uint4
// (group g of 8 k's), consumed straight from L2 by k_dec each step.
// gy = fc_w[128]@dec_k; gb = fc_b@dec_k + dec_b (both fp32).
// ---------------------------------------------------------------------------
__global__ __launch_bounds__(256) void k_prep(const float* __restrict__ fc_w,
                                              const float* __restrict__ fc_b,
                                              const float* __restrict__ dec_k,
                                              const float* __restrict__ dec_b,
                                              h2* __restrict__ Gp,
                                              float* __restrict__ gy,
                                              float* __restrict__ gb){
    int blk = blockIdx.x, tid = threadIdx.x;
    int u0 = tid, u1 = tid + 256;
    if (blk < 16){
        float a0[8], a1[8];
        #pragma unroll
        for (int r = 0; r < 8; ++r){ a0[r] = 0.f; a1[r] = 0.f; }
        for (int m = 0; m < 128; ++m){
            float d0 = dec_k[m*G4 + u0], d1 = dec_k[m*G4 + u1];
            #pragma unroll
            for (int r = 0; r < 8; ++r){
                float w = fc_w[(blk*8 + r)*HH + m];
                a0[r] += w * d0; a1[r] += w * d1;
            }
        }
        #pragma unroll
        for (int c = 0; c < 4; ++c){
            Gp[(blk*G4 + u0)*4 + c] = pk(a0[2*c], a0[2*c+1]);
            Gp[(blk*G4 + u1)*4 + c] = pk(a1[2*c], a1[2*c+1]);
        }
    } else if (blk == 16){
        float a0 = 0.f, a1 = 0.f;
        for (int m = 0; m < 128; ++m){
            float w = fc_w[128*HH + m];
            a0 += w * dec_k[m*G4 + u0]; a1 += w * dec_k[m*G4 + u1];
        }
        gy[u0] = a0; gy[u1] = a1;
    } else {
        float a0 = 0.f, a1 = 0.f;
        for (int m = 0; m < 128; ++m){
            float w = fc_b[m];
            a0 += w * dec_k[m*G4 + u0]; a1 += w * dec_k[m*G4 + u1];
        }
        gb[u0] = a0 + dec_b[u0]; gb[u1] = a1 + dec_b[u1];
    }
}

// ---------------------------------------------------------------------------
// k_enc: 512 threads, 1 gate-unit/thread. Round-6: all HSP broadcast reads
// widened to uint4 b128; 2-way split accumulator chains.
// ---------------------------------------------------------------------------
__global__ __launch_bounds__(512, 1) void k_enc(const float* __restrict__ inputs,
                                                const float* __restrict__ enc_k,
                                                const float* __restrict__ enc_r,
                                                const float* __restrict__ enc_b,
                                                const float* __restrict__ ae_w1,
                                                const float* __restrict__ ae_b1,
                                                const float* __restrict__ ae_w2,
                                                float* __restrict__ ws_xenc){
    extern __shared__ float lds[];
    float4* KL4  = (float4*)lds;          // [8][512] float4   (16384 words)
    float*  XPJT = lds + 16384;           // [128][33]         (4224)
    float*  XIN  = lds + 20608;           // [96][32]          (3072)
    float*  HST  = lds + 23680;           // 256: h, s (fp32 state)
    float*  PP   = lds + 23936;           // 512 partials / z
    float*  PE   = lds + 24448;           // 128
    float*  XT   = lds + 24576;           // 32
    float*  W2E  = lds + 24608;           // 128
    float*  AB1E = lds + 24736;           // 128
    h2*     HSP  = (h2*)(lds + 24864);    // 128: packed [h;s] pairs (16B-aligned)

    const int b = blockIdx.x, tid = threadIdx.x;
    const int u = tid, j7 = tid & 127, seg = tid >> 7;
    const float* xin_g = inputs + b*TT*FF;

    for (int i = tid; i < TT*FF; i += 512) XIN[i] = xin_g[i];
    for (int i = tid; i < 8*G4; i += 512){
        int f4 = i >> 9, uu = i & 511;
        float4 v;
        v.x = enc_k[(f4*4+0)*G4 + uu];
        v.y = enc_k[(f4*4+1)*G4 + uu];
        v.z = enc_k[(f4*4+2)*G4 + uu];
        v.w = enc_k[(f4*4+3)*G4 + uu];
        KL4[i] = v;
    }
    if (tid < 128){ W2E[tid] = ae_w2[tid]; AB1E[tid] = ae_b1[tid]; HSP[tid] = pk(0.f, 0.f); }
    if (tid < 256) HST[tid] = 0.f;

    // packed f16 weight columns in registers
    h2 wa_p[32], rp_e[64];
    #pragma unroll
    for (int i = 0; i < 32; ++i)
        wa_p[i] = pk(ae_w1[(seg*64 + 2*i)*HH + j7], ae_w1[(seg*64 + 2*i+1)*HH + j7]);
    #pragma unroll
    for (int i = 0; i < 64; ++i)
        rp_e[i] = pk(enc_r[(2*i)*G4 + u], enc_r[(2*i+1)*G4 + u]);
    const float eb = enc_b[u];

    __syncthreads();

    // XPJT[j][f] = sum_t x[t][f] * ae_w1[(256+t)*128 + j]  (time-invariant)
    {
        int j = tid & 127, fh = tid >> 7;
        float acc[8];
        #pragma unroll
        for (int i = 0; i < 8; ++i) acc[i] = 0.f;
        for (int t = 0; t < TT; ++t){
            float w = ae_w1[(256 + t)*HH + j];
            #pragma unroll
            for (int i = 0; i < 8; ++i) acc[i] += XIN[t*FF + fh*8 + i] * w;
        }
        #pragma unroll
        for (int i = 0; i < 8; ++i) XPJT[j*33 + fh*8 + i] = acc[i];
    }
    __syncthreads();

    const uint4* HSP4 = (const uint4*)HSP;

    for (int t = 0; t < TT; ++t){
        // PH-A: attention projection partials over packed [h;s] (b128 broadcasts)
        {
            float a0 = 0.f, a1 = 0.f;
            #pragma unroll
            for (int i4 = 0; i4 < 8; ++i4){
                uint4 q = HSP4[seg*8 + i4];
                a0 = fdot2(u2h(q.x), wa_p[i4*4+0], a0);
                a1 = fdot2(u2h(q.y), wa_p[i4*4+1], a1);
                a0 = fdot2(u2h(q.z), wa_p[i4*4+2], a0);
                a1 = fdot2(u2h(q.w), wa_p[i4*4+3], a1);
            }
            PP[tid] = a0 + a1;
        }
        __syncthreads();
        if (tid < 128) PE[tid] = PP[tid] + PP[128+tid] + PP[256+tid] + PP[384+tid] + AB1E[tid];
        __syncthreads();
        // PH-B: e[f] partials
        {
            int f = tid & 31, jg = tid >> 5;
            float acc = 0.f;
            #pragma unroll
            for (int i = 0; i < 8; ++i){
                int j = jg*8 + i;
                acc += ftanh(PE[j] + XPJT[j*33 + f]) * W2E[j];
            }
            PP[tid] = acc;
        }
        __syncthreads();
        // reduce + softmax + x_tilde on first 32 lanes
        if (tid < 32){
            float e = 0.f;
            #pragma unroll
            for (int g = 0; g < 16; ++g) e += PP[g*32 + tid];
            float m = e;
            #pragma unroll
            for (int d = 16; d; d >>= 1) m = fmaxf(m, __shfl_xor(m, d, 32));
            float p = fexp2((e - m)*LOG2E);
            float ss = p;
            #pragma unroll
            for (int d = 16; d; d >>= 1) ss += __shfl_xor(ss, d, 32);
            XT[tid] = p * frcp(ss) * XIN[t*FF + tid];
        }
        __syncthreads();
        // PH-D: z[u] = enc_b + x_tilde@enc_k (fp32 LDS) + h@enc_r (f16 regs, b128)
        {
            float z = eb, z2 = 0.f;
            #pragma unroll
            for (int f4 = 0; f4 < 8; ++f4){
                float4 xt4 = *(const float4*)&XT[f4*4];
                float4 kv = KL4[f4*G4 + u];
                z += xt4.x*kv.x + xt4.y*kv.y + xt4.z*kv.z + xt4.w*kv.w;
            }
            #pragma unroll
            for (int i4 = 0; i4 < 16; ++i4){
                uint4 q = HSP4[i4];
                z  = fdot2(u2h(q.x), rp_e[i4*4+0], z);
                z2 = fdot2(u2h(q.y), rp_e[i4*4+1], z2);
                z  = fdot2(u2h(q.z), rp_e[i4*4+2], z);
                z2 = fdot2(u2h(q.w), rp_e[i4*4+3], z2);
            }
            PP[u] = z + z2;
        }
        __syncthreads();
        // gates + packed-state update
        if (tid >= 128 && tid < 256){
            int j = tid - 128;
            float iv = fsigmoid(PP[j]);
            float fv = fsigmoid(PP[128 + j]);
            float gv = ftanh(PP[256 + j]);
            float ov = fsigmoid(PP[384 + j]);
            float cn = fv * HST[128 + j] + iv * gv;
            float hn = ov * ftanh(cn);
            HST[128 + j] = cn;
            HST[j] = hn;
            ws_xenc[(b*TT + t)*HH + j] = hn;
            float hn2 = __shfl_xor(hn, 1);
            float cn2 = __shfl_xor(cn, 1);
            if (!(j & 1)){
                HSP[j >> 1]        = pk(hn, hn2);   // h pairs
                HSP[64 + (j >> 1)] = pk(cn, cn2);   // s pairs
            }
        }
        __syncthreads();
    }
}

// ---------------------------------------------------------------------------
// k_xept: xeptT[b][j][t] = sum_k x_enc[b][t][k] * ad_w1[(256+k)*128 + j]
// ---------------------------------------------------------------------------
__global__ __launch_bounds__(256) void k_xept(const float* __restrict__ ws_xenc,
                                              const float* __restrict__ ad_w1,
                                              float* __restrict__ ws_xept){
    int b = blockIdx.x, q = blockIdx.y, tid = threadIdx.x;
    int j = tid & 127, th = tid >> 7;
    const float* xb = ws_xenc + b*TT*HH;
    float acc[12];
    #pragma unroll
    for (int i = 0; i < 12; ++i) acc[i] = 0.f;
    for (int k = 0; k < 128; ++k){
        float w = ad_w1[(256 + k)*HH + j];
        #pragma unroll
        for (int i = 0; i < 12; ++i){
            int tp = q*24 + th*12 + i;
            acc[i] += xb[tp*HH + k] * w;
        }
    }
    #pragma unroll
    for (int i = 0; i < 12; ++i){
        int tp = q*24 + th*12 + i;
        ws_xept[(b*HH + j)*TT + tp] = acc[i];
    }
}

// ---------------------------------------------------------------------------
// k_dec: Round-6 restructure. 1024 threads (16 waves, 4/SIMD), k-split:
//   u = tid&511 (gate unit), hf = tid>>9 (k-half) -> rp[32]+wp[16] = 48 regs.
// G read from global (L2-resident, [g][u] uint4 layout from k_prep).
// All LDS broadcasts b128. z-halves combine via PPZ[1024].
// ---------------------------------------------------------------------------
__global__ __launch_bounds__(1024, 1) void k_dec(const float* __restrict__ inputs,
                                                 const float* __restrict__ dec_r,
                                                 const float* __restrict__ ad_w1,
                                                 const float* __restrict__ ad_b1,
                                                 const float* __restrict__ ad_w2,
                                                 const float* __restrict__ ff_w,
                                                 const float* __restrict__ ff_b,
                                                 const h2* __restrict__ Gp,
                                                 const float* __restrict__ gy,
                                                 const float* __restrict__ gb,
                                                 const float* __restrict__ ws_xenc,
                                                 const float* __restrict__ ws_xept,
                                                 float* __restrict__ out){
    extern __shared__ float lds[];
    uint4* XE4 = (uint4*)lds;             // [12][128] uint4 (6144 words)
    float* PP  = lds + 6144;              // 1024 partials
    float* PPZ = lds + 7168;              // 1024 z-halves
    float* DST = lds + 8192;              // 256: d, c (fp32 state)
    float* APJ = lds + 8448;              // 128
    float* CTX = lds + 8576;              // 128
    float* W2L = lds + 8704;              // 128
    h2*    DCP = (h2*)(lds + 8832);       // 128: packed [d;c] pairs
    h2*    CXP = (h2*)(lds + 8960);       // 64: packed ctx pairs
    h2*    BEP = (h2*)(lds + 9024);       // 64 (48 used): packed beta pairs
    float* YV  = lds + 9088;              // 96: y_prev
    float* SCAL= lds + 9184;              // 8: [0]=1/sum

    const int b = blockIdx.x, tid = threadIdx.x;
    const int u = tid & 511, hf = tid >> 9;        // unit, k-half
    const int j7 = tid & 127, g8 = tid >> 7;       // attention mapping (g8: 0..7)

    {   // x_enc -> LDS f16 t-pairs, b128 writes
        const float* xe_g = ws_xenc + b*TT*HH;
        for (int i = tid; i < 12*HH; i += 1024){
            int t8 = i >> 7, k = i & 127;
            uint4 qq;
            qq.x = pku(xe_g[(t8*8 + 0)*HH + k], xe_g[(t8*8 + 1)*HH + k]);
            qq.y = pku(xe_g[(t8*8 + 2)*HH + k], xe_g[(t8*8 + 3)*HH + k]);
            qq.z = pku(xe_g[(t8*8 + 4)*HH + k], xe_g[(t8*8 + 5)*HH + k]);
            qq.w = pku(xe_g[(t8*8 + 6)*HH + k], xe_g[(t8*8 + 7)*HH + k]);
            XE4[i] = qq;
        }
    }
    if (tid < TT) YV[tid] = inputs[b*TT*FF + tid*FF + (FF-1)];
    if (tid < 128){ W2L[tid] = ad_w2[tid]; DCP[tid] = pk(0.f, 0.f); }
    if (tid < 256) DST[tid] = 0.f;

    // packed f16 weight columns (half k-range each): 48 regs total
    h2 rp[32], wp[16];
    #pragma unroll
    for (int i = 0; i < 32; ++i)
        rp[i] = pk(dec_r[(hf*64 + 2*i)*G4 + u], dec_r[(hf*64 + 2*i+1)*G4 + u]);
    #pragma unroll
    for (int i = 0; i < 16; ++i)
        wp[i] = pk(ad_w1[(g8*32 + 2*i)*HH + j7], ad_w1[(g8*32 + 2*i+1)*HH + j7]);
    const float gbr = gb[u], gyr = gy[u];
    const float ab1 = (tid < 128) ? ad_b1[tid] : 0.f;

    __syncthreads();

    const float* xeptb = ws_xept + b*HH*TT;
    const uint4* GQ   = (const uint4*)Gp;
    const uint4* DCP4 = (const uint4*)DCP;
    const uint4* CXP4 = (const uint4*)CXP;
    const uint4* BEP4 = (const uint4*)BEP;

    for (int t = 0; t < TT; ++t){
        // PH-1: attention projection partials (k-range g8*32..+31 of [d;c])
        {
            float a0 = 0.f, a1 = 0.f;
            #pragma unroll
            for (int i4 = 0; i4 < 4; ++i4){
                uint4 q = DCP4[g8*4 + i4];
                a0 = fdot2(u2h(q.x), wp[i4*4+0], a0);
                a1 = fdot2(u2h(q.y), wp[i4*4+1], a1);
                a0 = fdot2(u2h(q.z), wp[i4*4+2], a0);
                a1 = fdot2(u2h(q.w), wp[i4*4+3], a1);
            }
            PP[tid] = a0 + a1;
        }
        // PH-5a: z-half from d@dec_r (d-pairs hf*32..+31)
        float z = (hf == 0) ? (gbr + YV[t]*gyr) : 0.f;
        {
            float z2 = 0.f;
            #pragma unroll
            for (int i4 = 0; i4 < 8; ++i4){
                uint4 q = DCP4[hf*8 + i4];
                z  = fdot2(u2h(q.x), rp[i4*4+0], z);
                z2 = fdot2(u2h(q.y), rp[i4*4+1], z2);
                z  = fdot2(u2h(q.z), rp[i4*4+2], z);
                z2 = fdot2(u2h(q.w), rp[i4*4+3], z2);
            }
            z += z2;
        }
        __syncthreads();
        if (tid < 128){
            float s = ab1;
            #pragma unroll
            for (int g = 0; g < 8; ++g) s += PP[tid + 128*g];
            APJ[tid] = s;
        }
        __syncthreads();
        // PH-2: e[t'] partials (8 j-chunks of 16), b128 APJ/W2L broadcasts
        {
            int tp = tid & 127, jg = tid >> 7;
            float acc = 0.f;
            if (tp < TT){
                const float* xrow = xeptb + (jg*16)*TT + tp;
                #pragma unroll
                for (int q4 = 0; q4 < 4; ++q4){
                    float4 aj = *(const float4*)&APJ[jg*16 + q4*4];
                    float4 wj = *(const float4*)&W2L[jg*16 + q4*4];
                    acc += ftanh(aj.x + xrow[(q4*4+0)*TT]) * wj.x;
                    acc += ftanh(aj.y + xrow[(q4*4+1)*TT]) * wj.y;
                    acc += ftanh(aj.z + xrow[(q4*4+2)*TT]) * wj.z;
                    acc += ftanh(aj.w + xrow[(q4*4+3)*TT]) * wj.w;
                }
            }
            PP[tid] = acc;
        }
        __syncthreads();
        // reduce + softmax over 96 on wave 0; write packed beta pairs
        if (tid < 64){
            float ea = 0.f;
            #pragma unroll
            for (int g = 0; g < 8; ++g) ea += PP[tid + 128*g];
            float ebv = -3.0e38f;
            if (tid < 32){
                ebv = 0.f;
                #pragma unroll
                for (int g = 0; g < 8; ++g) ebv += PP[64 + tid + 128*g];
            }
            float m = fmaxf(ea, ebv);
            #pragma unroll
            for (int d = 32; d; d >>= 1) m = fmaxf(m, __shfl_xor(m, d, 64));
            float pa = fexp2((ea - m)*LOG2E);
            float pb = (tid < 32) ? fexp2((ebv - m)*LOG2E) : 0.f;
            float ss = pa + pb;
            #pragma unroll
            for (int d = 32; d; d >>= 1) ss += __shfl_xor(ss, d, 64);
            float pa2 = __shfl_xor(pa, 1);
            float pb2 = __shfl_xor(pb, 1);
            if (!(tid & 1)){
                BEP[tid >> 1] = pk(pa, pa2);
                if (tid < 32) BEP[32 + (tid >> 1)] = pk(pb, pb2);
            }
            if (tid == 0) SCAL[0] = frcp(ss);
        }
        __syncthreads();
        // PH-4: ctx partials; th<4 -> 2 t8-groups, th>=4 -> 1 group (12 total)
        {
            int k = tid & 127, th = tid >> 7;
            int t8a = (th < 4) ? th*2 : th + 4;
            int cnt = (th < 4) ? 2 : 1;
            float a = 0.f;
            for (int i = 0; i < cnt; ++i){
                int t8 = t8a + i;
                uint4 q  = XE4[t8*HH + k];
                uint4 bb = BEP4[t8];
                a = fdot2(u2h(q.x), u2h(bb.x), a);
                a = fdot2(u2h(q.y), u2h(bb.y), a);
                a = fdot2(u2h(q.z), u2h(bb.z), a);
                a = fdot2(u2h(q.w), u2h(bb.w), a);
            }
            PP[tid] = a;
        }
        __syncthreads();
        if (tid < 128){
            float s = 0.f;
            #pragma unroll
            for (int g = 0; g < 8; ++g) s += PP[tid + 128*g];
            float cv = s * SCAL[0];
            CTX[tid] = cv;
            float cv2 = __shfl_xor(cv, 1);
            if (!(tid & 1)) CXP[tid >> 1] = pk(cv, cv2);
        }
        __syncthreads();
        // PH-5b: z-half += ctx@G (G streamed from L2, groups hf*8..+7)
        {
            float z2 = 0.f;
            #pragma unroll
            for (int gi = 0; gi < 8; ++gi){
                int g = hf*8 + gi;
                uint4 q  = GQ[g*G4 + u];
                uint4 cc = CXP4[g];
                z  = fdot2(u2h(q.x), u2h(cc.x), z);
                z2 = fdot2(u2h(q.y), u2h(cc.y), z2);
                z  = fdot2(u2h(q.z), u2h(cc.z), z);
                z2 = fdot2(u2h(q.w), u2h(cc.w), z2);
            }
            PPZ[hf*512 + u] = z + z2;
        }
        __syncthreads();
        // PH-6: gates (combine z-halves) + packed-state update
        if (tid < 128){
            int j = tid;
            float zi = PPZ[j]       + PPZ[512 + j];
            float zf = PPZ[128 + j] + PPZ[640 + j];
            float zg = PPZ[256 + j] + PPZ[768 + j];
            float zo = PPZ[384 + j] + PPZ[896 + j];
            float iv = fsigmoid(zi);
            float fv = fsigmoid(zf);
            float gv = ftanh(zg);
            float ov = fsigmoid(zo);
            float cn = fv * DST[128 + j] + iv * gv;
            float hn = ov * ftanh(cn);
            DST[128 + j] = cn;
            DST[j] = hn;
            float hn2 = __shfl_xor(hn, 1);
            float cn2 = __shfl_xor(cn, 1);
            if (!(j & 1)){
                DCP[j >> 1]        = pk(hn, hn2);   // d pairs
                DCP[64 + (j >> 1)] = pk(cn, cn2);   // c pairs
            }
        }
        __syncthreads();
    }

    // output: y_pred = [d_n, ctx] @ ff_w + ff_b (fp32)
    {
        int jp = tid & 31, sg = tid >> 5;   // sg 0..31, k-range sg*8..+7
        float a = 0.f;
        #pragma unroll
        for (int kk = 0; kk < 8; ++kk){
            int k = sg*8 + kk;
            float val = (k < 128) ? DST[k] : CTX[k - 128];
            a += val * ff_w[k*FF + jp];
        }
        PP[sg*32 + jp] = a;
    }
    __syncthreads();
    if (tid < 32){
        float o = ff_b[tid];
        #pragma unroll
        for (int s = 0; s < 32; ++s) o += PP[s*32 + tid];
        out[b*FF + tid] = o;
    }
}

// ---------------------------------------------------------------------------
extern "C" void kernel_launch(void* const* d_in, const int* in_sizes, int n_in,
                              void* d_out, int out_size, void* d_ws, size_t ws_size,
                              hipStream_t stream) {
    const float* inputs = (const float*)d_in[0];
    const float* enc_k  = (const float*)d_in[1];
    const float* enc_r  = (const float*)d_in[2];
    const float* enc_b  = (const float*)d_in[3];
    const float* ae_w1  = (const float*)d_in[4];
    const float* ae_b1  = (const float*)d_in[5];
    const float* ae_w2  = (const float*)d_in[6];
    // d_in[7] = ae_b2 (softmax-invariant, unused)
    const float* dec_k  = (const float*)d_in[8];
    const float* dec_r  = (const float*)d_in[9];
    const float* dec_b  = (const float*)d_in[10];
    const float* ad_w1  = (const float*)d_in[11];
    const float* ad_b1  = (const float*)d_in[12];
    const float* ad_w2  = (const float*)d_in[13];
    // d_in[14] = ad_b2 (softmax-invariant, unused)
    const float* fc_w   = (const float*)d_in[15];
    const float* fc_b   = (const float*)d_in[16];
    const float* ff_w   = (const float*)d_in[17];
    const float* ff_b   = (const float*)d_in[18];

    float* ws      = (float*)d_ws;
    float* ws_xenc = ws;                     // 64*96*128 floats
    float* ws_xept = ws + 786432;            // 64*128*96 floats
    h2*    Gp      = (h2*)(ws + 1572864);    // 32768 h2 (128 KB)
    float* gy      = ws + 1605632;           // 512
    float* gb      = ws + 1606144;           // 512

    hipFuncSetAttribute((const void*)k_enc, hipFuncAttributeMaxDynamicSharedMemorySize, 99968);
    hipFuncSetAttribute((const void*)k_dec, hipFuncAttributeMaxDynamicSharedMemorySize, 36768);

    k_prep<<<18, 256, 0, stream>>>(fc_w, fc_b, dec_k, dec_b, Gp, gy, gb);
    k_enc<<<64, 512, 99968, stream>>>(inputs, enc_k, enc_r, enc_b, ae_w1, ae_b1, ae_w2, ws_xenc);
    k_xept<<<dim3(64, 4), 256, 0, stream>>>(ws_xenc, ad_w1, ws_xept);
    k_dec<<<64, 1024, 36768, stream>>>(inputs, dec_r, ad_w1, ad_b1, ad_w2, ff_w, ff_b,
                                       Gp, gy, gb, ws_xenc, ws_xept, (float*)d_out);
}

// Round 7
// 894.738 us; speedup vs baseline: 2.5648x; 1.1558x over previous
//
#include <hip/hip_runtime.h>

#define TT 96
#define FF 32
#define HH 128
#define G4 512
#define LOG2E 1.4426950408889634f

typedef _Float16 h2 __attribute__((ext_vector_type(2)));

__device__ __forceinline__ float fexp2(float x){ return __builtin_amdgcn_exp2f(x); }
__device__ __forceinline__ float frcp(float x){ return __builtin_amdgcn_rcpf(x); }
__device__ __forceinline__ float fsigmoid(float x){ return frcp(1.0f + fexp2(-LOG2E*x)); }
__device__ __forceinline__ float ftanh(float x){
    float u = fexp2(2.0f*LOG2E*x);
    return 1.0f - 2.0f*frcp(1.0f + u);
}
__device__ __forceinline__ h2 pk(float a, float b){
    h2 r; r.x = (_Float16)a; r.y = (_Float16)b; return r;   // RNE cvt
}
__device__ __forceinline__ unsigned pku(float a, float b){
    return __builtin_bit_cast(unsigned, pk(a, b));
}
__device__ __forceinline__ h2 u2h(unsigned v){ return __builtin_bit_cast(h2, v); }
__device__ __forceinline__ float fdot2(h2 a, h2 b, float c){
#if __has_builtin(__builtin_amdgcn_fdot2)
    return __builtin_amdgcn_fdot2(a, b, c, false);          // v_dot2_f32_f16
#else
    return c + (float)a.x*(float)b.x + (float)a.y*(float)b.y;
#endif
}

// ---------------------------------------------------------------------------
// k_prep: G = fc_w[0:128]@dec_k packed to f16 pairs, layout [g][u] uint4
// (group g of 8 k's), consumed straight from L2 by k_dec each step.
// gy = fc_w[128]@dec_k; gb = fc_b@dec_k + dec_b (both fp32).
// ---------------------------------------------------------------------------
__global__ __launch_bounds__(256) void k_prep(const float* __restrict__ fc_w,
                                              const float* __restrict__ fc_b,
                                              const float* __restrict__ dec_k,
                                              const float* __restrict__ dec_b,
                                              h2* __restrict__ Gp,
                                              float* __restrict__ gy,
                                              float* __restrict__ gb){
    int blk = blockIdx.x, tid = threadIdx.x;
    int u0 = tid, u1 = tid + 256;
    if (blk < 16){
        float a0[8], a1[8];
        #pragma unroll
        for (int r = 0; r < 8; ++r){ a0[r] = 0.f; a1[r] = 0.f; }
        for (int m = 0; m < 128; ++m){
            float d0 = dec_k[m*G4 + u0], d1 = dec_k[m*G4 + u1];
            #pragma unroll
            for (int r = 0; r < 8; ++r){
                float w = fc_w[(blk*8 + r)*HH + m];
                a0[r] += w * d0; a1[r] += w * d1;
            }
        }
        #pragma unroll
        for (int c = 0; c < 4; ++c){
            Gp[(blk*G4 + u0)*4 + c] = pk(a0[2*c], a0[2*c+1]);
            Gp[(blk*G4 + u1)*4 + c] = pk(a1[2*c], a1[2*c+1]);
        }
    } else if (blk == 16){
        float a0 = 0.f, a1 = 0.f;
        for (int m = 0; m < 128; ++m){
            float w = fc_w[128*HH + m];
            a0 += w * dec_k[m*G4 + u0]; a1 += w * dec_k[m*G4 + u1];
        }
        gy[u0] = a0; gy[u1] = a1;
    } else {
        float a0 = 0.f, a1 = 0.f;
        for (int m = 0; m < 128; ++m){
            float w = fc_b[m];
            a0 += w * dec_k[m*G4 + u0]; a1 += w * dec_k[m*G4 + u1];
        }
        gb[u0] = a0 + dec_b[u0]; gb[u1] = a1 + dec_b[u1];
    }
}

// ---------------------------------------------------------------------------
// k_enc: Round-7 restructure -> 1024 threads (16 waves), k-split like k_dec:
// u = tid&511 (gate unit), hf = tid>>9 (k-half): rp_e[32]+wa_p[16] = 48 regs.
// enc_k f16 in LDS (b128). h@enc_r z-half off critical path; z in register
// across barriers; PPZ combine in gates. Softmax without max-subtraction
// (|e| <= ~5, exp2 safe in fp32).
// ---------------------------------------------------------------------------
__global__ __launch_bounds__(1024, 1) void k_enc(const float* __restrict__ inputs,
                                                 const float* __restrict__ enc_k,
                                                 const float* __restrict__ enc_r,
                                                 const float* __restrict__ enc_b,
                                                 const float* __restrict__ ae_w1,
                                                 const float* __restrict__ ae_b1,
                                                 const float* __restrict__ ae_w2,
                                                 float* __restrict__ ws_xenc){
    extern __shared__ float lds[];
    uint4* KLH4 = (uint4*)lds;            // [4][512] uint4 (enc_k f16) = 8192 floats
    float* XPJT = lds + 8192;             // [128][33] = 4224
    float* XIN  = lds + 12416;            // [96][32]  = 3072
    float* HST  = lds + 15488;            // 256 (h, s fp32 state)
    float* PP   = lds + 15744;            // 1024 partials
    float* PPZ  = lds + 16768;            // 1024 z-halves
    float* PE   = lds + 17792;            // 128
    float* W2E  = lds + 17920;            // 128
    float* AB1E = lds + 18048;            // 128
    h2*    HSP  = (h2*)(lds + 18176);     // 128 h2: packed [h;s] pairs
    h2*    XTP  = (h2*)(lds + 18240);     // 16 h2: packed x_tilde pairs
    // total 18256 floats = 73024 B

    const int b = blockIdx.x, tid = threadIdx.x;
    const int u = tid & 511, hf = tid >> 9;
    const int j7 = tid & 127, g8 = tid >> 7;
    const float* xin_g = inputs + b*TT*FF;

    for (int i = tid; i < TT*FF; i += 1024) XIN[i] = xin_g[i];
    for (int i = tid; i < 2048; i += 1024){      // enc_k -> f16 LDS
        int f8 = i >> 9, uu = i & 511;
        uint4 q;
        q.x = pku(enc_k[(f8*8+0)*G4+uu], enc_k[(f8*8+1)*G4+uu]);
        q.y = pku(enc_k[(f8*8+2)*G4+uu], enc_k[(f8*8+3)*G4+uu]);
        q.z = pku(enc_k[(f8*8+4)*G4+uu], enc_k[(f8*8+5)*G4+uu]);
        q.w = pku(enc_k[(f8*8+6)*G4+uu], enc_k[(f8*8+7)*G4+uu]);
        KLH4[i] = q;
    }
    if (tid < 128){ W2E[tid] = ae_w2[tid]; AB1E[tid] = ae_b1[tid]; HSP[tid] = pk(0.f, 0.f); }
    if (tid < 256) HST[tid] = 0.f;

    h2 rp_e[32], wa_p[16];
    #pragma unroll
    for (int i = 0; i < 32; ++i)
        rp_e[i] = pk(enc_r[(hf*64 + 2*i)*G4 + u], enc_r[(hf*64 + 2*i+1)*G4 + u]);
    #pragma unroll
    for (int i = 0; i < 16; ++i)
        wa_p[i] = pk(ae_w1[(g8*32 + 2*i)*HH + j7], ae_w1[(g8*32 + 2*i+1)*HH + j7]);
    const float eb = (hf == 0) ? enc_b[u] : 0.f;
    __syncthreads();

    {   // XPJT[j][f] = sum_t x[t][f]*ae_w1[(256+t)*128+j]  (time-invariant)
        int j = tid & 127, fh = tid >> 7;
        float a0=0.f, a1=0.f, a2=0.f, a3=0.f;
        for (int t = 0; t < TT; ++t){
            float w = ae_w1[(256 + t)*HH + j];
            const float* xr = &XIN[t*FF + fh*4];
            a0 += xr[0]*w; a1 += xr[1]*w; a2 += xr[2]*w; a3 += xr[3]*w;
        }
        XPJT[j*33 + fh*4 + 0] = a0;
        XPJT[j*33 + fh*4 + 1] = a1;
        XPJT[j*33 + fh*4 + 2] = a2;
        XPJT[j*33 + fh*4 + 3] = a3;
    }
    __syncthreads();

    const uint4* HSP4 = (const uint4*)HSP;
    const uint4* XTP4 = (const uint4*)XTP;

    for (int t = 0; t < TT; ++t){
        // PH-A: attention proj partials (k-range g8*32..+31 of [h;s])
        {
            float a0 = 0.f, a1 = 0.f;
            #pragma unroll
            for (int i4 = 0; i4 < 4; ++i4){
                uint4 q = HSP4[g8*4 + i4];
                a0 = fdot2(u2h(q.x), wa_p[i4*4+0], a0);
                a1 = fdot2(u2h(q.y), wa_p[i4*4+1], a1);
                a0 = fdot2(u2h(q.z), wa_p[i4*4+2], a0);
                a1 = fdot2(u2h(q.w), wa_p[i4*4+3], a1);
            }
            PP[tid] = a0 + a1;
        }
        // z-half: h@enc_r (off critical path; uses HSP from prev gates barrier)
        float z = eb;
        {
            float z2 = 0.f;
            #pragma unroll
            for (int i4 = 0; i4 < 8; ++i4){
                uint4 q = HSP4[hf*8 + i4];
                z  = fdot2(u2h(q.x), rp_e[i4*4+0], z);
                z2 = fdot2(u2h(q.y), rp_e[i4*4+1], z2);
                z  = fdot2(u2h(q.z), rp_e[i4*4+2], z);
                z2 = fdot2(u2h(q.w), rp_e[i4*4+3], z2);
            }
            z += z2;
        }
        __syncthreads();
        if (tid < 128){
            float s = AB1E[tid];
            #pragma unroll
            for (int g = 0; g < 8; ++g) s += PP[tid + 128*g];
            PE[tid] = s;
        }
        __syncthreads();
        // PH-B: e[f] partials (32 j-groups of 4)
        {
            int f = tid & 31, jg = tid >> 5;
            float acc = 0.f;
            #pragma unroll
            for (int i = 0; i < 4; ++i){
                int j = jg*4 + i;
                acc += ftanh(PE[j] + XPJT[j*33 + f]) * W2E[j];
            }
            PP[tid] = acc;
        }
        __syncthreads();
        // reduce + softmax (no max-sub) + x_tilde pack on first 32 lanes
        if (tid < 32){
            float e = 0.f;
            #pragma unroll
            for (int g = 0; g < 32; ++g) e += PP[g*32 + tid];
            float p = fexp2(e * LOG2E);
            float ss = p;
            #pragma unroll
            for (int d = 16; d; d >>= 1) ss += __shfl_xor(ss, d, 32);
            float xt = p * frcp(ss) * XIN[t*FF + tid];
            float xt2 = __shfl_xor(xt, 1);
            if (!(tid & 1)) XTP[tid >> 1] = pk(xt, xt2);
        }
        __syncthreads();
        // PH-D: z-half += x_tilde@enc_k (f16 LDS, b128), store z-half
        {
            float z2 = 0.f;
            #pragma unroll
            for (int c = 0; c < 2; ++c){
                int f8 = hf*2 + c;
                uint4 kq = KLH4[f8*512 + u];
                uint4 xq = XTP4[f8];
                z  = fdot2(u2h(kq.x), u2h(xq.x), z);
                z2 = fdot2(u2h(kq.y), u2h(xq.y), z2);
                z  = fdot2(u2h(kq.z), u2h(xq.z), z);
                z2 = fdot2(u2h(kq.w), u2h(xq.w), z2);
            }
            PPZ[hf*512 + u] = z + z2;
        }
        __syncthreads();
        // gates (combine z-halves) + packed-state update
        if (tid < 128){
            int j = tid;
            float zi = PPZ[j]       + PPZ[512 + j];
            float zf = PPZ[128 + j] + PPZ[640 + j];
            float zg = PPZ[256 + j] + PPZ[768 + j];
            float zo = PPZ[384 + j] + PPZ[896 + j];
            float iv = fsigmoid(zi);
            float fv = fsigmoid(zf);
            float gv = ftanh(zg);
            float ov = fsigmoid(zo);
            float cn = fv * HST[128 + j] + iv * gv;
            float hn = ov * ftanh(cn);
            HST[128 + j] = cn;
            HST[j] = hn;
            ws_xenc[(b*TT + t)*HH + j] = hn;
            float hn2 = __shfl_xor(hn, 1);
            float cn2 = __shfl_xor(cn, 1);
            if (!(j & 1)){
                HSP[j >> 1]        = pk(hn, hn2);   // h pairs
                HSP[64 + (j >> 1)] = pk(cn, cn2);   // s pairs
            }
        }
        __syncthreads();
    }
}

// ---------------------------------------------------------------------------
// k_xept: xeptT[b][j][t] = sum_k x_enc[b][t][k] * ad_w1[(256+k)*128 + j]
// ---------------------------------------------------------------------------
__global__ __launch_bounds__(256) void k_xept(const float* __restrict__ ws_xenc,
                                              const float* __restrict__ ad_w1,
                                              float* __restrict__ ws_xept){
    int b = blockIdx.x, q = blockIdx.y, tid = threadIdx.x;
    int j = tid & 127, th = tid >> 7;
    const float* xb = ws_xenc + b*TT*HH;
    float acc[12];
    #pragma unroll
    for (int i = 0; i < 12; ++i) acc[i] = 0.f;
    for (int k = 0; k < 128; ++k){
        float w = ad_w1[(256 + k)*HH + j];
        #pragma unroll
        for (int i = 0; i < 12; ++i){
            int tp = q*24 + th*12 + i;
            acc[i] += xb[tp*HH + k] * w;
        }
    }
    #pragma unroll
    for (int i = 0; i < 12; ++i){
        int tp = q*24 + th*12 + i;
        ws_xept[(b*HH + j)*TT + tp] = acc[i];
    }
}

// ---------------------------------------------------------------------------
// k_dec: 1024 threads, k-split (round-6 structure). Round-7: xept preloaded
// into LDS (PH-2 reads conflict-free LDS instead of strided global);
// softmax without max-subtraction.
// ---------------------------------------------------------------------------
__global__ __launch_bounds__(1024, 1) void k_dec(const float* __restrict__ inputs,
                                                 const float* __restrict__ dec_r,
                                                 const float* __restrict__ ad_w1,
                                                 const float* __restrict__ ad_b1,
                                                 const float* __restrict__ ad_w2,
                                                 const float* __restrict__ ff_w,
                                                 const float* __restrict__ ff_b,
                                                 const h2* __restrict__ Gp,
                                                 const float* __restrict__ gy,
                                                 const float* __restrict__ gb,
                                                 const float* __restrict__ ws_xenc,
                                                 const float* __restrict__ ws_xept,
                                                 float* __restrict__ out){
    extern __shared__ float lds[];
    uint4* XE4 = (uint4*)lds;             // [12][128] uint4 = 6144 floats
    float* XPT = lds + 6144;              // [128][96] xept  = 12288
    float* PP  = lds + 18432;             // 1024 partials
    float* PPZ = lds + 19456;             // 1024 z-halves
    float* DST = lds + 20480;             // 256: d, c (fp32 state)
    float* APJ = lds + 20736;             // 128
    float* CTX = lds + 20864;             // 128
    float* W2L = lds + 20992;             // 128
    h2*    DCP = (h2*)(lds + 21120);      // 128 h2: packed [d;c] pairs
    h2*    CXP = (h2*)(lds + 21184);      // 64 h2: packed ctx pairs
    h2*    BEP = (h2*)(lds + 21216);      // 64 h2 (48 used): packed beta pairs
    float* YV  = lds + 21248;             // 96: y_prev
    float* SCAL= lds + 21344;             // 8: [0]=1/sum
    // total 21352 floats = 85408 B

    const int b = blockIdx.x, tid = threadIdx.x;
    const int u = tid & 511, hf = tid >> 9;        // unit, k-half
    const int j7 = tid & 127, g8 = tid >> 7;       // attention mapping

    {   // x_enc -> LDS f16 t-pairs, b128 writes
        const float* xe_g = ws_xenc + b*TT*HH;
        for (int i = tid; i < 12*HH; i += 1024){
            int t8 = i >> 7, k = i & 127;
            uint4 qq;
            qq.x = pku(xe_g[(t8*8 + 0)*HH + k], xe_g[(t8*8 + 1)*HH + k]);
            qq.y = pku(xe_g[(t8*8 + 2)*HH + k], xe_g[(t8*8 + 3)*HH + k]);
            qq.z = pku(xe_g[(t8*8 + 4)*HH + k], xe_g[(t8*8 + 5)*HH + k]);
            qq.w = pku(xe_g[(t8*8 + 6)*HH + k], xe_g[(t8*8 + 7)*HH + k]);
            XE4[i] = qq;
        }
    }
    {   // xept -> LDS fp32 (one-time, coalesced)
        const float* xp_g = ws_xept + b*HH*TT;
        for (int i = tid; i < HH*TT; i += 1024) XPT[i] = xp_g[i];
    }
    if (tid < TT) YV[tid] = inputs[b*TT*FF + tid*FF + (FF-1)];
    if (tid < 128){ W2L[tid] = ad_w2[tid]; DCP[tid] = pk(0.f, 0.f); }
    if (tid < 256) DST[tid] = 0.f;

    // packed f16 weight columns (half k-range each)
    h2 rp[32], wp[16];
    #pragma unroll
    for (int i = 0; i < 32; ++i)
        rp[i] = pk(dec_r[(hf*64 + 2*i)*G4 + u], dec_r[(hf*64 + 2*i+1)*G4 + u]);
    #pragma unroll
    for (int i = 0; i < 16; ++i)
        wp[i] = pk(ad_w1[(g8*32 + 2*i)*HH + j7], ad_w1[(g8*32 + 2*i+1)*HH + j7]);
    const float gbr = gb[u], gyr = gy[u];
    const float ab1 = (tid < 128) ? ad_b1[tid] : 0.f;

    __syncthreads();

    const uint4* GQ   = (const uint4*)Gp;
    const uint4* DCP4 = (const uint4*)DCP;
    const uint4* CXP4 = (const uint4*)CXP;
    const uint4* BEP4 = (const uint4*)BEP;

    for (int t = 0; t < TT; ++t){
        // PH-1: attention proj partials (k-range g8*32..+31 of [d;c])
        {
            float a0 = 0.f, a1 = 0.f;
            #pragma unroll
            for (int i4 = 0; i4 < 4; ++i4){
                uint4 q = DCP4[g8*4 + i4];
                a0 = fdot2(u2h(q.x), wp[i4*4+0], a0);
                a1 = fdot2(u2h(q.y), wp[i4*4+1], a1);
                a0 = fdot2(u2h(q.z), wp[i4*4+2], a0);
                a1 = fdot2(u2h(q.w), wp[i4*4+3], a1);
            }
            PP[tid] = a0 + a1;
        }
        // PH-5a: z-half from d@dec_r
        float z = (hf == 0) ? (gbr + YV[t]*gyr) : 0.f;
        {
            float z2 = 0.f;
            #pragma unroll
            for (int i4 = 0; i4 < 8; ++i4){
                uint4 q = DCP4[hf*8 + i4];
                z  = fdot2(u2h(q.x), rp[i4*4+0], z);
                z2 = fdot2(u2h(q.y), rp[i4*4+1], z2);
                z  = fdot2(u2h(q.z), rp[i4*4+2], z);
                z2 = fdot2(u2h(q.w), rp[i4*4+3], z2);
            }
            z += z2;
        }
        __syncthreads();
        if (tid < 128){
            float s = ab1;
            #pragma unroll
            for (int g = 0; g < 8; ++g) s += PP[tid + 128*g];
            APJ[tid] = s;
        }
        __syncthreads();
        // PH-2: e[t'] partials (8 j-chunks of 16) — xept from LDS
        {
            int tp = tid & 127, jg = tid >> 7;
            float acc = 0.f;
            if (tp < TT){
                const float* xrow = &XPT[(jg*16)*TT + tp];
                #pragma unroll
                for (int q4 = 0; q4 < 4; ++q4){
                    float4 aj = *(const float4*)&APJ[jg*16 + q4*4];
                    float4 wj = *(const float4*)&W2L[jg*16 + q4*4];
                    acc += ftanh(aj.x + xrow[(q4*4+0)*TT]) * wj.x;
                    acc += ftanh(aj.y + xrow[(q4*4+1)*TT]) * wj.y;
                    acc += ftanh(aj.z + xrow[(q4*4+2)*TT]) * wj.z;
                    acc += ftanh(aj.w + xrow[(q4*4+3)*TT]) * wj.w;
                }
            }
            PP[tid] = acc;
        }
        __syncthreads();
        // reduce + softmax over 96 on wave 0 (no max-sub); packed beta pairs
        if (tid < 64){
            float ea = 0.f;
            #pragma unroll
            for (int g = 0; g < 8; ++g) ea += PP[tid + 128*g];
            float pa = fexp2(ea * LOG2E);
            float pb = 0.f;
            if (tid < 32){
                float ebv = 0.f;
                #pragma unroll
                for (int g = 0; g < 8; ++g) ebv += PP[64 + tid + 128*g];
                pb = fexp2(ebv * LOG2E);
            }
            float ss = pa + pb;
            #pragma unroll
            for (int d = 32; d; d >>= 1) ss += __shfl_xor(ss, d, 64);
            float pa2 = __shfl_xor(pa, 1);
            float pb2 = __shfl_xor(pb, 1);
            if (!(tid & 1)){
                BEP[tid >> 1] = pk(pa, pa2);
                if (tid < 32) BEP[32 + (tid >> 1)] = pk(pb, pb2);
            }
            if (tid == 0) SCAL[0] = frcp(ss);
        }
        __syncthreads();
        // PH-4: ctx partials; th<4 -> 2 t8-groups, th>=4 -> 1 group
        {
            int k = tid & 127, th = tid >> 7;
            int t8a = (th < 4) ? th*2 : th + 4;
            int cnt = (th < 4) ? 2 : 1;
            float a = 0.f;
            for (int i = 0; i < cnt; ++i){
                int t8 = t8a + i;
                uint4 q  = XE4[t8*HH + k];
                uint4 bb = BEP4[t8];
                a = fdot2(u2h(q.x), u2h(bb.x), a);
                a = fdot2(u2h(q.y), u2h(bb.y), a);
                a = fdot2(u2h(q.z), u2h(bb.z), a);
                a = fdot2(u2h(q.w), u2h(bb.w), a);
            }
            PP[tid] = a;
        }
        __syncthreads();
        if (tid < 128){
            float s = 0.f;
            #pragma unroll
            for (int g = 0; g < 8; ++g) s += PP[tid + 128*g];
            float cv = s * SCAL[0];
            CTX[tid] = cv;
            float cv2 = __shfl_xor(cv, 1);
            if (!(tid & 1)) CXP[tid >> 1] = pk(cv, cv2);
        }
        __syncthreads();
        // PH-5b: z-half += ctx@G (G streamed from L2, groups hf*8..+7)
        {
            float z2 = 0.f;
            #pragma unroll
            for (int gi = 0; gi < 8; ++gi){
                int g = hf*8 + gi;
                uint4 q  = GQ[g*G4 + u];
                uint4 cc = CXP4[g];
                z  = fdot2(u2h(q.x), u2h(cc.x), z);
                z2 = fdot2(u2h(q.y), u2h(cc.y), z2);
                z  = fdot2(u2h(q.z), u2h(cc.z), z);
                z2 = fdot2(u2h(q.w), u2h(cc.w), z2);
            }
            PPZ[hf*512 + u] = z + z2;
        }
        __syncthreads();
        // PH-6: gates (combine z-halves) + packed-state update
        if (tid < 128){
            int j = tid;
            float zi = PPZ[j]       + PPZ[512 + j];
            float zf = PPZ[128 + j] + PPZ[640 + j];
            float zg = PPZ[256 + j] + PPZ[768 + j];
            float zo = PPZ[384 + j] + PPZ[896 + j];
            float iv = fsigmoid(zi);
            float fv = fsigmoid(zf);
            float gv = ftanh(zg);
            float ov = fsigmoid(zo);
            float cn = fv * DST[128 + j] + iv * gv;
            float hn = ov * ftanh(cn);
            DST[128 + j] = cn;
            DST[j] = hn;
            float hn2 = __shfl_xor(hn, 1);
            float cn2 = __shfl_xor(cn, 1);
            if (!(j & 1)){
                DCP[j >> 1]        = pk(hn, hn2);   // d pairs
                DCP[64 + (j >> 1)] = pk(cn, cn2);   // c pairs
            }
        }
        __syncthreads();
    }

    // output: y_pred = [d_n, ctx] @ ff_w + ff_b (fp32)
    {
        int jp = tid & 31, sg = tid >> 5;   // sg 0..31, k-range sg*8..+7
        float a = 0.f;
        #pragma unroll
        for (int kk = 0; kk < 8; ++kk){
            int k = sg*8 + kk;
            float val = (k < 128) ? DST[k] : CTX[k - 128];
            a += val * ff_w[k*FF + jp];
        }
        PP[sg*32 + jp] = a;
    }
    __syncthreads();
    if (tid < 32){
        float o = ff_b[tid];
        #pragma unroll
        for (int s = 0; s < 32; ++s) o += PP[s*32 + tid];
        out[b*FF + tid] = o;
    }
}

// ---------------------------------------------------------------------------
extern "C" void kernel_launch(void* const* d_in, const int* in_sizes, int n_in,
                              void* d_out, int out_size, void* d_ws, size_t ws_size,
                              hipStream_t stream) {
    const float* inputs = (const float*)d_in[0];
    const float* enc_k  = (const float*)d_in[1];
    const float* enc_r  = (const float*)d_in[2];
    const float* enc_b  = (const float*)d_in[3];
    const float* ae_w1  = (const float*)d_in[4];
    const float* ae_b1  = (const float*)d_in[5];
    const float* ae_w2  = (const float*)d_in[6];
    // d_in[7] = ae_b2 (softmax-invariant, unused)
    const float* dec_k  = (const float*)d_in[8];
    const float* dec_r  = (const float*)d_in[9];
    const float* dec_b  = (const float*)d_in[10];
    const float* ad_w1  = (const float*)d_in[11];
    const float* ad_b1  = (const float*)d_in[12];
    const float* ad_w2  = (const float*)d_in[13];
    // d_in[14] = ad_b2 (softmax-invariant, unused)
    const float* fc_w   = (const float*)d_in[15];
    const float* fc_b   = (const float*)d_in[16];
    const float* ff_w   = (const float*)d_in[17];
    const float* ff_b   = (const float*)d_in[18];

    float* ws      = (float*)d_ws;
    float* ws_xenc = ws;                     // 64*96*128 floats
    float* ws_xept = ws + 786432;            // 64*128*96 floats
    h2*    Gp      = (h2*)(ws + 1572864);    // 32768 h2 (128 KB)
    float* gy      = ws + 1605632;           // 512
    float* gb      = ws + 1606144;           // 512

    hipFuncSetAttribute((const void*)k_enc, hipFuncAttributeMaxDynamicSharedMemorySize, 73024);
    hipFuncSetAttribute((const void*)k_dec, hipFuncAttributeMaxDynamicSharedMemorySize, 85408);

    k_prep<<<18, 256, 0, stream>>>(fc_w, fc_b, dec_k, dec_b, Gp, gy, gb);
    k_enc<<<64, 1024, 73024, stream>>>(inputs, enc_k, enc_r, enc_b, ae_w1, ae_b1, ae_w2, ws_xenc);
    k_xept<<<dim3(64, 4), 256, 0, stream>>>(ws_xenc, ad_w1, ws_xept);
    k_dec<<<64, 1024, 85408, stream>>>(inputs, dec_r, ad_w1, ad_b1, ad_w2, ff_w, ff_b,
                                       Gp, gy, gb, ws_xenc, ws_xept, (float*)d_out);
}